// Round 4
// baseline (712.449 us; speedup 1.0000x reference)
//
#include <hip/hip_runtime.h>
#include <cstddef>

// ---------------- problem constants ----------------
constexpr int BSz = 8;     // batch
constexpr int Bb  = 8;     // blocks (episodic banks)
constexpr int Mm  = 512;   // memory slots
constexpr int Dd  = 128;   // feature dim
constexpr int Nn  = 1024;  // tokens
constexpr float NEGV = -1e30f;

typedef unsigned short ushort_t;
typedef __attribute__((ext_vector_type(8))) short short8v;  // 8 bf16 (4 VGPRs)
typedef __attribute__((ext_vector_type(4))) float f32x4;    // 4 fp32 acc

__device__ __forceinline__ float softplusf(float x) {
    return (x > 20.f) ? x : log1pf(expf(x));
}
// f32 -> bf16, round-to-nearest-even
__device__ __forceinline__ unsigned short f2bf(float f) {
    unsigned u = __float_as_uint(f);
    u += 0x7fffu + ((u >> 16) & 1u);
    return (unsigned short)(u >> 16);
}
__device__ __forceinline__ unsigned pack2bf(float a, float b) {
    return (unsigned)f2bf(a) | ((unsigned)f2bf(b) << 16);
}
__device__ __forceinline__ f32x4 mfma16(short8v a, short8v b, f32x4 c) {
    return __builtin_amdgcn_mfma_f32_16x16x32_bf16(a, b, c, 0, 0, 0);
}

// ---- stage K chunk (64 x 128 f32 -> bf16 LDS [64][136], row-major) ----
__device__ __forceinline__ void stage_K64(const float* __restrict__ src,
                                          ushort_t (*kl)[136], int tid) {
    const float4* s4 = (const float4*)src;
    #pragma unroll
    for (int it = 0; it < 8; ++it) {
        int i = tid + it * 256;
        int m = i >> 5, c = i & 31;
        float4 v = s4[i];
        uint2 w;
        w.x = pack2bf(v.x, v.y);
        w.y = pack2bf(v.z, v.w);
        *(uint2*)&kl[m][c * 4] = w;
    }
}

// ---- stage V chunk transposed: logical vt[d][m] = bf16(V[m][d]),
//      stored at column m ^ (((d>>2)&7)<<2) to break bank conflicts. ----
__device__ __forceinline__ void stage_VT(const float* __restrict__ src,
                                         ushort_t (*vt)[72], int tid) {
    const int wv = tid >> 6, l = tid & 63;
    const int c = l & 31, mh = l >> 5;         // mh in {0,1}
    #pragma unroll
    for (int it = 0; it < 8; ++it) {
        int pi = wv * 8 + it;                  // row-pair 0..31
        int m0 = pi * 2;
        float4 mine = *(const float4*)(src + (size_t)(m0 + mh) * Dd + c * 4);
        float4 oth;
        oth.x = __shfl_xor(mine.x, 32);
        oth.y = __shfl_xor(mine.y, 32);
        oth.z = __shfl_xor(mine.z, 32);
        oth.w = __shfl_xor(mine.w, 32);
        float a0 = mh ? oth.z  : mine.x;
        float a1 = mh ? mine.z : oth.x;
        float b0 = mh ? oth.w  : mine.y;
        float b1 = mh ? mine.w : oth.y;
        int d0 = c * 4 + mh * 2;
        int sw = ((d0 >> 2) & 7) << 2;
        int col = m0 ^ sw;
        *(unsigned*)&vt[d0][col]     = pack2bf(a0, a1);
        *(unsigned*)&vt[d0 + 1][col] = pack2bf(b0, b1);
    }
}

// ---- stage w_norm chunk transposed with per-row scale (fallback k2b) ----
__device__ __forceinline__ void stage_WVT(const float* __restrict__ src,
                                          const float* sinv,
                                          ushort_t (*vt)[72], int tid) {
    const int wv = tid >> 6, l = tid & 63;
    const int c = l & 31, mh = l >> 5;
    #pragma unroll
    for (int it = 0; it < 8; ++it) {
        int pi = wv * 8 + it;
        int m0 = pi * 2;
        float inv = sinv[m0 + mh];
        float4 mine = *(const float4*)(src + (size_t)(m0 + mh) * Dd + c * 4);
        mine.x *= inv; mine.y *= inv; mine.z *= inv; mine.w *= inv;
        float4 oth;
        oth.x = __shfl_xor(mine.x, 32);
        oth.y = __shfl_xor(mine.y, 32);
        oth.z = __shfl_xor(mine.z, 32);
        oth.w = __shfl_xor(mine.w, 32);
        float a0 = mh ? oth.z  : mine.x;
        float a1 = mh ? mine.z : oth.x;
        float b0 = mh ? oth.w  : mine.y;
        float b1 = mh ? mine.w : oth.y;
        int d0 = c * 4 + mh * 2;
        int sw = ((d0 >> 2) & 7) << 2;
        int col = m0 ^ sw;
        *(unsigned*)&vt[d0][col]     = pack2bf(a0, a1);
        *(unsigned*)&vt[d0 + 1][col] = pack2bf(b0, b1);
    }
}

// ---- transpose normalized LDS rows into vt image (prep k0w) ----
__device__ __forceinline__ void transpose_yl_to_vt(const float (*yl)[132],
                                                   ushort_t (*vt)[72], int tid) {
    const int wv = tid >> 6, l = tid & 63;
    const int c = l & 31, mh = l >> 5;
    #pragma unroll
    for (int it = 0; it < 8; ++it) {
        int pi = wv * 8 + it;
        int m0 = pi * 2;
        float4 mine = *(const float4*)&yl[m0 + mh][c * 4];
        float4 oth;
        oth.x = __shfl_xor(mine.x, 32);
        oth.y = __shfl_xor(mine.y, 32);
        oth.z = __shfl_xor(mine.z, 32);
        oth.w = __shfl_xor(mine.w, 32);
        float a0 = mh ? oth.z  : mine.x;
        float a1 = mh ? mine.z : oth.x;
        float b0 = mh ? oth.w  : mine.y;
        float b1 = mh ? mine.w : oth.y;
        int d0 = c * 4 + mh * 2;
        int sw = ((d0 >> 2) & 7) << 2;
        int col = m0 ^ sw;
        *(unsigned*)&vt[d0][col]     = pack2bf(a0, a1);
        *(unsigned*)&vt[d0 + 1][col] = pack2bf(b0, b1);
    }
}

// ---- fragment readers ----
__device__ __forceinline__ short8v read_kfrag(const ushort_t (*kl)[136],
                                              int mt, int ck, int g, int q) {
    union { short8v s; uint4 u; } r;
    r.u = *(const uint4*)&kl[mt * 16 + q][ck * 32 + g * 8];
    return r.s;
}
__device__ __forceinline__ short8v build_yfrag(const float (*yl)[132], int row, int ck, int g) {
    float4 v0 = *(const float4*)&yl[row][ck * 32 + g * 8];
    float4 v1 = *(const float4*)&yl[row][ck * 32 + g * 8 + 4];
    union { short8v s; uint4 u; } r;
    r.u.x = pack2bf(v0.x, v0.y);
    r.u.y = pack2bf(v0.z, v0.w);
    r.u.z = pack2bf(v1.x, v1.y);
    r.u.w = pack2bf(v1.z, v1.w);
    return r.s;
}
// build yfrag from a global f32 row
__device__ __forceinline__ short8v build_gfrag(const float* __restrict__ yr, int ck, int g) {
    float4 a = *(const float4*)(yr + ck * 32 + g * 8);
    float4 c = *(const float4*)(yr + ck * 32 + g * 8 + 4);
    union { short8v s; uint4 u; } r;
    r.u.x = pack2bf(a.x, a.y);
    r.u.y = pack2bf(a.z, a.w);
    r.u.z = pack2bf(c.x, c.y);
    r.u.w = pack2bf(c.z, c.w);
    return r.s;
}
__device__ __forceinline__ short8v read_vfrag(const ushort_t (*vt)[72],
                                              int kc, int dt, int g, int q) {
    int d = dt * 16 + q;
    int sw = ((d >> 2) & 7) << 2;
    uint2 lo = *(const uint2*)&vt[d][(kc * 32 + 4 * g) ^ sw];
    uint2 hi = *(const uint2*)&vt[d][(kc * 32 + 16 + 4 * g) ^ sw];
    union { short8v s; uint4 u; } r;
    r.u.x = lo.x; r.u.y = lo.y; r.u.z = hi.x; r.u.w = hi.y;
    return r.s;
}

// ---- LDS tile writes from prefetched registers (pre path) ----
__device__ __forceinline__ void kwrite(ushort_t (*kl)[136], const uint4* pf, int tid) {
    #pragma unroll
    for (int j = 0; j < 4; ++j) {
        int i = tid + j * 256;
        *(uint4*)&kl[i >> 4][(i & 15) * 8] = pf[j];
    }
}
__device__ __forceinline__ void vwrite(ushort_t (*vt)[72], const uint4* pf, int tid) {
    #pragma unroll
    for (int j = 0; j < 4; ++j) {
        int i = tid + j * 256;
        *(uint4*)&vt[i >> 3][(i & 7) * 8] = pf[j];
    }
}

// ---- activity-mask builder ----
__device__ __forceinline__ void build_mask(const float* __restrict__ emS, size_t pair,
                                           int g, unsigned long long& mlo,
                                           unsigned long long& mhi) {
    mlo = 0ull; mhi = 0ull;
    const float4* sp = (const float4*)(emS + pair * Mm);
    #pragma unroll 8
    for (int t = 0; t < 32; ++t) {
        float4 s = sp[t * 4 + g];
        unsigned long long bits = (s.x > 0.f ? 1ull : 0ull) | (s.y > 0.f ? 2ull : 0ull)
                                | (s.z > 0.f ? 4ull : 0ull) | (s.w > 0.f ? 8ull : 0ull);
        if (t < 16) mlo |= bits << (t * 4);
        else        mhi |= bits << ((t - 16) * 4);
    }
}

// =====================================================================
// Prep kernel k0kv: emK -> bf16 row image; emV -> bf16 transposed image.
// 1D grid 512, swizzled so XCD (id%8) == b (matches k1/k2a consumers).
// =====================================================================
__global__ __launch_bounds__(256) void k0kv(
    const float* __restrict__ emK, const float* __restrict__ emV,
    ushort_t* __restrict__ Kbf, ushort_t* __restrict__ Vtb)
{
    const int id = blockIdx.x;
    const int b = id & 7, t = id >> 3, mc = t & 7, bs = t >> 3;
    const int tid = threadIdx.x;
    const size_t pair = (size_t)(bs * Bb + b);
    __shared__ ushort_t vt[128][72];
    {
        const float4* s4 = (const float4*)(emK + (pair * Mm + (size_t)mc * 64) * Dd);
        uint2* dst = (uint2*)(Kbf + pair * 65536u + (size_t)mc * 8192u);
        #pragma unroll
        for (int it = 0; it < 8; ++it) {
            int i = tid + it * 256;
            float4 v = s4[i];
            uint2 w;
            w.x = pack2bf(v.x, v.y);
            w.y = pack2bf(v.z, v.w);
            dst[i] = w;
        }
    }
    stage_VT(emV + (pair * Mm + (size_t)mc * 64) * Dd, vt, tid);
    __syncthreads();
    {
        uint4* dst = (uint4*)(Vtb + pair * 65536u + (size_t)mc * 8192u);
        #pragma unroll
        for (int it = 0; it < 4; ++it) {
            int i = tid + it * 256;
            dst[i] = *(const uint4*)&vt[i >> 3][(i & 7) * 8];
        }
    }
}

// =====================================================================
// Prep kernel k0w: w_cand -> w_norm bf16 row image + transposed image + nrm
// 1D grid 128, swizzled so XCD == bs (matches k2b consumer).
// =====================================================================
__global__ __launch_bounds__(256) void k0w(
    const float* __restrict__ w_cand, ushort_t* __restrict__ wnr,
    ushort_t* __restrict__ wnT, float* __restrict__ nrmb)
{
    const int id = blockIdx.x;
    const int bs = id & 7, nb = (id >> 3) * 64;
    const int tid = threadIdx.x;
    const int wv = tid >> 6, l = tid & 63, g = l >> 4, q = l & 15;
    __shared__ float yl[64][132];
    __shared__ ushort_t vt[128][72];
    {
        const float4* s4 = (const float4*)(w_cand + ((size_t)bs * Nn + nb) * Dd);
        #pragma unroll
        for (int it = 0; it < 8; ++it) {
            int i = tid + it * 256;
            *(float4*)&yl[i >> 5][(i & 31) * 4] = s4[i];
        }
    }
    __syncthreads();
    #pragma unroll
    for (int r = 0; r < 4; ++r) {
        int row = wv * 16 + 4 * g + r;
        float v8[8]; float p = 0.f;
        #pragma unroll
        for (int dt = 0; dt < 8; ++dt) { float v = yl[row][dt * 16 + q]; v8[dt] = v; p += v * v; }
        #pragma unroll
        for (int off = 1; off < 16; off <<= 1) p += __shfl_xor(p, off);
        float nrm = fmaxf(sqrtf(p), 1e-12f);
        float inv = 1.f / nrm;
        if (q == 0) nrmb[(size_t)bs * Nn + nb + row] = nrm;
        #pragma unroll
        for (int dt = 0; dt < 8; ++dt) yl[row][dt * 16 + q] = v8[dt] * inv;
    }
    __syncthreads();
    {
        uint4* dst = (uint4*)(wnr + (size_t)bs * 131072u) + (size_t)nb * 16u;
        #pragma unroll
        for (int j = 0; j < 4; ++j) {
            int i = tid + j * 256;
            int row = i >> 4, c8 = i & 15;
            float4 a = *(const float4*)&yl[row][c8 * 8];
            float4 c = *(const float4*)&yl[row][c8 * 8 + 4];
            uint4 w;
            w.x = pack2bf(a.x, a.y); w.y = pack2bf(a.z, a.w);
            w.z = pack2bf(c.x, c.y); w.w = pack2bf(c.z, c.w);
            dst[i] = w;
        }
    }
    transpose_yl_to_vt(yl, vt, tid);
    __syncthreads();
    {
        uint4* dst = (uint4*)(wnT + (size_t)bs * 131072u) + (size_t)(nb >> 6) * 1024u;
        #pragma unroll
        for (int it = 0; it < 4; ++it) {
            int i = tid + it * 256;
            dst[i] = *(const uint4*)&vt[i >> 3][(i & 7) * 8];
        }
    }
}

// =====================================================================
// Kernel 1 (split): one attention step. step=0: y_in = seed, write y to
// y_em region. step=1: y_in = y_em, write final y - seed.
// 1D grid 1024; swizzle: b = id&7 (XCD-groups each pair's 16 n-blocks),
// n0 = ((id>>3)&15)*64, bs = id>>7. LDS 37 KB -> up to 4 blocks/CU.
// =====================================================================
__global__ __launch_bounds__(256) void k1_step(
    const float* __restrict__ seed, const ushort_t* __restrict__ Kbf,
    const ushort_t* __restrict__ Vtb, const float* __restrict__ emS,
    const float* __restrict__ w1, const float* __restrict__ w2,
    const float* __restrict__ gb, const float* __restrict__ rtau,
    float* __restrict__ y_em, int step)
{
    const int id = blockIdx.x;
    const int b = id & 7, bs = id >> 7, n0 = ((id >> 3) & 15) << 6;
    const int tid = threadIdx.x;
    const int wv = tid >> 6, l = tid & 63, g = l >> 4, q = l & 15;

    __shared__ ushort_t kl[64][136];
    __shared__ ushort_t vt[128][72];
    __shared__ float sw1[Dd], sw2[Dd], sgb[Dd];

    const float itau = 1.f / (softplusf(rtau[b]) + 0.1f);
    const size_t pair = (size_t)(bs * Bb + b);
    const uint4* Ksrc = (const uint4*)(Kbf + pair * 65536u);
    const uint4* Vsrc = (const uint4*)(Vtb + pair * 65536u);

    if (tid < Dd) {
        sw1[tid] = w1[b * Dd + tid];
        sw2[tid] = w2[b * Dd + tid];
        sgb[tid] = gb[b * Dd + tid];
    }
    unsigned long long mlo, mhi;
    build_mask(emS, pair, g, mlo, mhi);

    // y B-frags from global (lane-local row n = n0 + wv*16 + q)
    short8v yf[4];
    {
        int n = n0 + wv * 16 + q;
        const float* yr = step ? (y_em + (((size_t)bs * Nn + n) * Bb + b) * Dd)
                               : (seed + ((size_t)bs * Nn + n) * Dd);
        #pragma unroll
        for (int ck = 0; ck < 4; ++ck) yf[ck] = build_gfrag(yr, ck, g);
    }
    uint4 kpf[4], vpf[4];
    #pragma unroll
    for (int j = 0; j < 4; ++j) { kpf[j] = Ksrc[tid + j * 256]; vpf[j] = Vsrc[tid + j * 256]; }

    const f32x4 Z4 = {0.f, 0.f, 0.f, 0.f};
    float m_run = NEGV, l_run = 0.f;
    f32x4 dacc[8];
    #pragma unroll
    for (int dt = 0; dt < 8; ++dt) dacc[dt] = Z4;

    for (int mc = 0; mc < 8; ++mc) {
        kwrite(kl, kpf, tid);
        vwrite(vt, vpf, tid);
        __syncthreads();
        if (mc < 7) {          // T14: next chunk loads in flight under compute
            #pragma unroll
            for (int j = 0; j < 4; ++j) {
                kpf[j] = Ksrc[(mc + 1) * 1024 + tid + j * 256];
                vpf[j] = Vsrc[(mc + 1) * 1024 + tid + j * 256];
            }
        }

        f32x4 sc[4];
        #pragma unroll
        for (int mt = 0; mt < 4; ++mt) {
            f32x4 acc = Z4;
            #pragma unroll
            for (int ck = 0; ck < 4; ++ck)
                acc = mfma16(read_kfrag(kl, mt, ck, g, q), yf[ck], acc);
            sc[mt] = acc;
        }
        unsigned au = (unsigned)(((mc < 4) ? mlo : mhi) >> ((mc & 3) * 16)) & 0xFFFFu;
        #pragma unroll
        for (int mt = 0; mt < 4; ++mt)
            #pragma unroll
            for (int r = 0; r < 4; ++r)
                sc[mt][r] = ((au >> (mt * 4 + r)) & 1u) ? sc[mt][r] * itau : NEGV;
        float cm = NEGV;
        #pragma unroll
        for (int mt = 0; mt < 4; ++mt)
            #pragma unroll
            for (int r = 0; r < 4; ++r) cm = fmaxf(cm, sc[mt][r]);
        cm = fmaxf(cm, __shfl_xor(cm, 16));
        cm = fmaxf(cm, __shfl_xor(cm, 32));
        float mnew = fmaxf(m_run, cm);
        float corr = __expf(m_run - mnew);
        unsigned pw[8];
        float psum = 0.f;
        #pragma unroll
        for (int mt = 0; mt < 4; ++mt)
            #pragma unroll
            for (int r = 0; r < 4; r += 2) {
                float e0 = __expf(sc[mt][r]     - mnew);
                float e1 = __expf(sc[mt][r + 1] - mnew);
                psum += e0 + e1;
                pw[mt * 2 + (r >> 1)] = pack2bf(e0, e1);
            }
        psum += __shfl_xor(psum, 16);
        psum += __shfl_xor(psum, 32);
        l_run = l_run * corr + psum;
        m_run = mnew;
        float cr[4];
        #pragma unroll
        for (int r = 0; r < 4; ++r) cr[r] = __shfl(corr, 4 * g + r);
        #pragma unroll
        for (int dt = 0; dt < 8; ++dt)
            #pragma unroll
            for (int r = 0; r < 4; ++r) dacc[dt][r] *= cr[r];
        union { short8v s; uint4 u; } pa0, pa1;
        pa0.u = make_uint4(pw[0], pw[1], pw[2], pw[3]);
        pa1.u = make_uint4(pw[4], pw[5], pw[6], pw[7]);
        #pragma unroll
        for (int dt = 0; dt < 8; ++dt) {
            f32x4 acc = dacc[dt];
            acc = mfma16(pa0.s, read_vfrag(vt, 0, dt, g, q), acc);
            acc = mfma16(pa1.s, read_vfrag(vt, 1, dt, g, q), acc);
            dacc[dt] = acc;
        }
        __syncthreads();
    }
    // ---- gate + output (lane-local rows 4g+r, cols dt*16 + q) ----
    float inv = (m_run != NEGV) ? 1.f / l_run : 0.f;
    float ivr[4];
    #pragma unroll
    for (int r = 0; r < 4; ++r) ivr[r] = __shfl(inv, 4 * g + r);
    #pragma unroll
    for (int r = 0; r < 4; ++r) {
        int n = n0 + wv * 16 + 4 * g + r;
        const float* yr = step ? (y_em + (((size_t)bs * Nn + n) * Bb + b) * Dd)
                               : (seed + ((size_t)bs * Nn + n) * Dd);
        const float* sr = seed + ((size_t)bs * Nn + n) * Dd;
        float* yo = y_em + (((size_t)bs * Nn + n) * Bb + b) * Dd;
        #pragma unroll
        for (int dt = 0; dt < 8; ++dt) {
            int d = dt * 16 + q;
            float y0 = yr[d];
            float del = dacc[dt][r] * ivr[r];
            float z = sw1[d] * y0 + sw2[d] * del + sgb[d];
            float gte = 1.f / (1.f + __expf(-z));
            float yn = y0 + gte * del;
            yo[d] = step ? (yn - sr[d]) : yn;
        }
    }
}

// =====================================================================
// Kernel 2a (pre): novelty path, swizzled 1D grid (XCD == b)
// =====================================================================
__global__ __launch_bounds__(256) void k2a_pre(
    const float* __restrict__ w_cand, const float* __restrict__ surprise,
    const ushort_t* __restrict__ Kbf, const ushort_t* __restrict__ Vtb,
    const ushort_t* __restrict__ wnr, const float* __restrict__ emS,
    const float* __restrict__ rtau, const float* __restrict__ rtauw,
    float* __restrict__ delta_em, float* newV /* stats alias */)
{
    const int id = blockIdx.x;
    const int b = id & 7, bs = id >> 7, n0 = ((id >> 3) & 15) << 6;
    const int tid = threadIdx.x;
    const int wv = tid >> 6, l = tid & 63, g = l >> 4, q = l & 15;

    __shared__ ushort_t kl[64][136];
    __shared__ ushort_t vt[128][72];

    const float itau = 1.f / (softplusf(rtau[b]) + 0.1f);
    const float itw  = 1.f / (softplusf(rtauw[b]) + 0.1f);
    const size_t pair = (size_t)(bs * Bb + b);
    const uint4* Ksrc = (const uint4*)(Kbf + pair * 65536u);
    const uint4* Vsrc = (const uint4*)(Vtb + pair * 65536u);
    float* stats = newV + pair * (size_t)(Mm * Dd) + 448 * Dd;

    unsigned long long mlo, mhi;
    build_mask(emS, pair, g, mlo, mhi);

    short8v yf[4];
    {
        const uint4* wr = (const uint4*)(wnr + (size_t)bs * 131072u
                                         + (size_t)(n0 + wv * 16 + q) * 128u);
        #pragma unroll
        for (int ck = 0; ck < 4; ++ck) {
            union { short8v s; uint4 u; } r;
            r.u = wr[ck * 4 + g];
            yf[ck] = r.s;
        }
    }
    uint4 kpf[4], vpf[4];
    #pragma unroll
    for (int j = 0; j < 4; ++j) { kpf[j] = Ksrc[tid + j * 256]; vpf[j] = Vsrc[tid + j * 256]; }

    const f32x4 Z4 = {0.f, 0.f, 0.f, 0.f};
    float m1 = NEGV, l1 = 0.f, m2 = NEGV, s2 = 0.f;
    f32x4 dacc[8];
    #pragma unroll
    for (int dt = 0; dt < 8; ++dt) dacc[dt] = Z4;

    for (int mc = 0; mc < 8; ++mc) {
        kwrite(kl, kpf, tid);
        vwrite(vt, vpf, tid);
        __syncthreads();
        if (mc < 7) {
            #pragma unroll
            for (int j = 0; j < 4; ++j) {
                kpf[j] = Ksrc[(mc + 1) * 1024 + tid + j * 256];
                vpf[j] = Vsrc[(mc + 1) * 1024 + tid + j * 256];
            }
        }

        f32x4 sc[4];   // RAW dots
        #pragma unroll
        for (int mt = 0; mt < 4; ++mt) {
            f32x4 acc = Z4;
            #pragma unroll
            for (int ck = 0; ck < 4; ++ck)
                acc = mfma16(read_kfrag(kl, mt, ck, g, q), yf[ck], acc);
            sc[mt] = acc;
        }
        unsigned au = (unsigned)(((mc < 4) ? mlo : mhi) >> ((mc & 3) * 16)) & 0xFFFFu;

        float cm2 = NEGV;
        #pragma unroll
        for (int mt = 0; mt < 4; ++mt)
            #pragma unroll
            for (int r = 0; r < 4; ++r) {
                float v = ((au >> (mt * 4 + r)) & 1u) ? sc[mt][r] * itw : NEGV;
                cm2 = fmaxf(cm2, v);
            }
        cm2 = fmaxf(cm2, __shfl_xor(cm2, 16));
        cm2 = fmaxf(cm2, __shfl_xor(cm2, 32));
        float mn2 = fmaxf(m2, cm2);
        float c2 = __expf(m2 - mn2);
        float ps2 = 0.f;
        #pragma unroll
        for (int mt = 0; mt < 4; ++mt)
            #pragma unroll
            for (int r = 0; r < 4; ++r) {
                float v = ((au >> (mt * 4 + r)) & 1u) ? sc[mt][r] * itw : NEGV;
                ps2 += __expf(v - mn2);
            }
        ps2 += __shfl_xor(ps2, 16);
        ps2 += __shfl_xor(ps2, 32);
        s2 = s2 * c2 + ps2;
        m2 = mn2;

        #pragma unroll
        for (int mt = 0; mt < 4; ++mt)
            #pragma unroll
            for (int r = 0; r < 4; ++r)
                sc[mt][r] = ((au >> (mt * 4 + r)) & 1u) ? sc[mt][r] * itau : NEGV;
        float cm = NEGV;
        #pragma unroll
        for (int mt = 0; mt < 4; ++mt)
            #pragma unroll
            for (int r = 0; r < 4; ++r) cm = fmaxf(cm, sc[mt][r]);
        cm = fmaxf(cm, __shfl_xor(cm, 16));
        cm = fmaxf(cm, __shfl_xor(cm, 32));
        float mnew = fmaxf(m1, cm);
        float corr = __expf(m1 - mnew);
        unsigned pw[8];
        float psum = 0.f;
        #pragma unroll
        for (int mt = 0; mt < 4; ++mt)
            #pragma unroll
            for (int r = 0; r < 4; r += 2) {
                float e0 = __expf(sc[mt][r]     - mnew);
                float e1 = __expf(sc[mt][r + 1] - mnew);
                psum += e0 + e1;
                pw[mt * 2 + (r >> 1)] = pack2bf(e0, e1);
            }
        psum += __shfl_xor(psum, 16);
        psum += __shfl_xor(psum, 32);
        l1 = l1 * corr + psum;
        m1 = mnew;
        float cr[4];
        #pragma unroll
        for (int r = 0; r < 4; ++r) cr[r] = __shfl(corr, 4 * g + r);
        #pragma unroll
        for (int dt = 0; dt < 8; ++dt)
            #pragma unroll
            for (int r = 0; r < 4; ++r) dacc[dt][r] *= cr[r];
        union { short8v s; uint4 u; } pa0, pa1;
        pa0.u = make_uint4(pw[0], pw[1], pw[2], pw[3]);
        pa1.u = make_uint4(pw[4], pw[5], pw[6], pw[7]);
        #pragma unroll
        for (int dt = 0; dt < 8; ++dt) {
            f32x4 acc = dacc[dt];
            acc = mfma16(pa0.s, read_vfrag(vt, 0, dt, g, q), acc);
            acc = mfma16(pa1.s, read_vfrag(vt, 1, dt, g, q), acc);
            dacc[dt] = acc;
        }
        __syncthreads();
    }
    if (g == 0) {
        int n = n0 + wv * 16 + q;
        stats[1024 + n] = m2;
        stats[2048 + n] = s2;
    }
    float inv1 = (m1 != NEGV) ? 1.f / l1 : 0.f;
    float ivr[4];
    #pragma unroll
    for (int r = 0; r < 4; ++r) ivr[r] = __shfl(inv1, 4 * g + r);
    #pragma unroll
    for (int r = 0; r < 4; ++r) {
        int n = n0 + wv * 16 + 4 * g + r;
        const float* wcr = w_cand + ((size_t)bs * Nn + n) * Dd;
        const float* spr = surprise + ((size_t)bs * Nn + n) * Dd;
        float pe = 0.f, ps = 0.f, wcv[8];
        #pragma unroll
        for (int dt = 0; dt < 8; ++dt) {
            float wc = wcr[dt * 16 + q];
            float rec = dacc[dt][r] * ivr[r];
            float df = wc - rec;
            pe += df * df;
            float sv = spr[dt * 16 + q];
            ps += sv * sv;
            wcv[dt] = wc;
        }
        #pragma unroll
        for (int off = 1; off < 16; off <<= 1) {
            pe += __shfl_xor(pe, off);
            ps += __shfl_xor(ps, off);
        }
        float novl = 0.5f * sqrtf(ps) + 0.5f * sqrtf(pe);
        if (q == 0) stats[n] = novl;
        float* der = delta_em + (((size_t)bs * Nn + n) * Bb + b) * Dd;
        #pragma unroll
        for (int dt = 0; dt < 8; ++dt) der[dt * 16 + q] = novl * wcv[dt];
    }
}

// =====================================================================
// Kernel 2b (pre): route recompute + updates; swizzled 1D grid (XCD==bs).
// phase 0: 448 blocks (mt 0..6); phase 1: 64 blocks (mt=7, retires stats).
// =====================================================================
__global__ __launch_bounds__(256) void k2b_pre(
    const ushort_t* __restrict__ wnr, const ushort_t* __restrict__ wnT,
    const ushort_t* __restrict__ Kbf,
    const float* __restrict__ emK, const float* __restrict__ emV,
    const float* __restrict__ emS, const float* __restrict__ emAge,
    const float* __restrict__ g_em, const float* __restrict__ rtauw,
    const float* __restrict__ nrmb,
    float* __restrict__ newK, float* newV /* aliases stats */,
    float* __restrict__ newAge, float* __restrict__ newS, int phase)
{
    const int id = blockIdx.x;
    const int bs = id & 7;
    const int t = id >> 3;
    const int b  = phase ? t : t / 7;
    const int mt = phase ? 7 : t % 7;
    const int m0 = mt * 64;
    const int tid = threadIdx.x;
    const int wv = tid >> 6, l = tid & 63, g = l >> 4, q = l & 15;

    __shared__ ushort_t klw[64][136];
    __shared__ ushort_t vtw[128][72];
    __shared__ float sh_rm[Nn], sh_f[Nn], sh_fn[Nn];

    const float itw = 1.f / (softplusf(rtauw[b]) + 0.1f);
    const float gv = g_em[bs * Bb + b];
    const size_t pair = (size_t)(bs * Bb + b);
    const float* stats = newV + pair * (size_t)(Mm * Dd) + 448 * Dd;

    for (int i = tid; i < Nn; i += 256) {
        float nv = stats[i];
        float rm = stats[1024 + i];
        float rs = stats[2048 + i];
        float nr = nrmb[(size_t)bs * Nn + i];
        sh_rm[i] = rm;
        float f = nv / rs;
        sh_f[i]  = f;
        sh_fn[i] = f * nr;
    }

    const int myM = m0 + wv * 16 + q;
    short8v kf[4];
    {
        const uint4* kr = (const uint4*)(Kbf + pair * 65536u + (size_t)myM * 128u);
        #pragma unroll
        for (int ck = 0; ck < 4; ++ck) {
            union { short8v s; uint4 u; } r;
            r.u = kr[ck * 4 + g];
            kf[ck] = r.s;
        }
    }
    const bool act = (emS[pair * Mm + myM] > 0.f);

    const uint4* Wr = (const uint4*)(wnr + (size_t)bs * 131072u);
    const uint4* Wt = (const uint4*)(wnT + (size_t)bs * 131072u);
    uint4 wpf[4], tpf[4];
    #pragma unroll
    for (int j = 0; j < 4; ++j) { wpf[j] = Wr[tid + j * 256]; tpf[j] = Wt[tid + j * 256]; }

    const f32x4 Z4 = {0.f, 0.f, 0.f, 0.f};
    f32x4 uKacc[8], uVacc[8];
    #pragma unroll
    for (int dt = 0; dt < 8; ++dt) { uKacc[dt] = Z4; uVacc[dt] = Z4; }
    float den = 0.f;

    for (int nc = 0; nc < 16; ++nc) {
        const int nb = nc * 64;
        kwrite(klw, wpf, tid);
        vwrite(vtw, tpf, tid);
        __syncthreads();
        if (nc < 15) {
            #pragma unroll
            for (int j = 0; j < 4; ++j) {
                wpf[j] = Wr[(nc + 1) * 1024 + tid + j * 256];
                tpf[j] = Wt[(nc + 1) * 1024 + tid + j * 256];
            }
        }

        f32x4 sc[4];
        #pragma unroll
        for (int nt = 0; nt < 4; ++nt) {
            f32x4 acc = Z4;
            #pragma unroll
            for (int ck = 0; ck < 4; ++ck)
                acc = mfma16(read_kfrag(klw, nt, ck, g, q), kf[ck], acc);
            sc[nt] = acc;
        }
        unsigned pwK[8], pwV[8];
        #pragma unroll
        for (int nt = 0; nt < 4; ++nt) {
            float w0[4], w1[4];
            #pragma unroll
            for (int r = 0; r < 4; ++r) {
                int nl = nb + nt * 16 + 4 * g + r;
                float val = act ? sc[nt][r] * itw : NEGV;
                float E = __expf(val - sh_rm[nl]);
                float a = sh_f[nl] * E;
                w0[r] = a;
                w1[r] = sh_fn[nl] * E;
                den += a;
            }
            pwK[nt * 2 + 0] = pack2bf(w0[0], w0[1]);
            pwK[nt * 2 + 1] = pack2bf(w0[2], w0[3]);
            pwV[nt * 2 + 0] = pack2bf(w1[0], w1[1]);
            pwV[nt * 2 + 1] = pack2bf(w1[2], w1[3]);
        }
        union { short8v s; uint4 u; } paK0, paK1, paV0, paV1;
        paK0.u = make_uint4(pwK[0], pwK[1], pwK[2], pwK[3]);
        paK1.u = make_uint4(pwK[4], pwK[5], pwK[6], pwK[7]);
        paV0.u = make_uint4(pwV[0], pwV[1], pwV[2], pwV[3]);
        paV1.u = make_uint4(pwV[4], pwV[5], pwV[6], pwV[7]);
        #pragma unroll
        for (int dt = 0; dt < 8; ++dt) {
            short8v b0 = read_vfrag(vtw, 0, dt, g, q);
            short8v b1 = read_vfrag(vtw, 1, dt, g, q);
            uKacc[dt] = mfma16(paK0.s, b0, uKacc[dt]);
            uKacc[dt] = mfma16(paK1.s, b1, uKacc[dt]);
            uVacc[dt] = mfma16(paV0.s, b0, uVacc[dt]);
            uVacc[dt] = mfma16(paV1.s, b1, uVacc[dt]);
        }
        __syncthreads();
    }

    // ---- epilogue ----
    den += __shfl_xor(den, 16);
    den += __shfl_xor(den, 32);
    float invd = 1.f / fmaxf(den, 1e-8f);
    float alpha = fminf(gv * den * (1.f / (float)Nn), 1.f);

    float pr[4] = {0.f, 0.f, 0.f, 0.f};
    #pragma unroll
    for (int dt = 0; dt < 8; ++dt)
        #pragma unroll
        for (int r = 0; r < 4; ++r) { float u = uKacc[dt][r]; pr[r] += u * u; }
    #pragma unroll
    for (int r = 0; r < 4; ++r) {
        #pragma unroll
        for (int off = 1; off < 16; off <<= 1) pr[r] += __shfl_xor(pr[r], off);
    }
    float alr[4], idr[4], inr[4];
    #pragma unroll
    for (int r = 0; r < 4; ++r) {
        alr[r] = __shfl(alpha, 4 * g + r);
        idr[r] = __shfl(invd,  4 * g + r);
        inr[r] = 1.f / fmaxf(sqrtf(pr[r]) * idr[r], 1e-12f);
    }
    #pragma unroll
    for (int r = 0; r < 4; ++r) {
        size_t rowoff = (pair * Mm + m0 + wv * 16 + 4 * g + r) * (size_t)Dd;
        float a = alr[r], om = 1.f - a, idv = idr[r], in = inr[r];
        #pragma unroll
        for (int dt = 0; dt < 8; ++dt) {
            int d = dt * 16 + q;
            float kv = emK[rowoff + d];
            float vv = emV[rowoff + d];
            newK[rowoff + d] = om * kv + a * uKacc[dt][r] * idv * in;
            newV[rowoff + d] = om * vv + a * uVacc[dt][r] * idv;
        }
    }
    if (q == 0) {
        #pragma unroll
        for (int r = 0; r < 4; ++r) {
            int m = m0 + wv * 16 + 4 * g + r;
            float a = alr[r];
            float S = emS[pair * Mm + m];
            newS[pair * Mm + m] = fminf(fmaxf(S + a, 0.f), 3.0f);
            newAge[pair * Mm + m] = emAge[pair * Mm + m] * (1.f - a);
        }
    }
}

// =====================================================================
// ===================== FALLBACK KERNELS (verified) ===================
// Used only when the workspace is too small for the prestaged images.
// =====================================================================
__global__ __launch_bounds__(256) void k1_fb(
    const float* __restrict__ seed, const float* __restrict__ emK, const float* __restrict__ emV,
    const float* __restrict__ emS, const float* __restrict__ w1, const float* __restrict__ w2,
    const float* __restrict__ gb, const float* __restrict__ rtau, float* __restrict__ y_em)
{
    const int bs = blockIdx.z, b = blockIdx.y, n0 = blockIdx.x * 64;
    const int tid = threadIdx.x;
    const int wv = tid >> 6, l = tid & 63, g = l >> 4, q = l & 15;

    __shared__ float yl[64][132];
    __shared__ ushort_t kl[64][136];
    __shared__ ushort_t vt[128][72];
    __shared__ float sw1[Dd], sw2[Dd], sgb[Dd];

    const float itau = 1.f / (softplusf(rtau[b]) + 0.1f);
    const size_t pair = (size_t)(bs * Bb + b);
    const float* Kb = emK + pair * (size_t)(Mm * Dd);
    const float* Vb = emV + pair * (size_t)(Mm * Dd);

    if (tid < Dd) {
        sw1[tid] = w1[b * Dd + tid];
        sw2[tid] = w2[b * Dd + tid];
        sgb[tid] = gb[b * Dd + tid];
    }
    unsigned long long mlo, mhi;
    build_mask(emS, pair, g, mlo, mhi);
    {
        const float4* s4 = (const float4*)(seed + ((size_t)bs * Nn + n0) * Dd);
        #pragma unroll
        for (int it = 0; it < 8; ++it) {
            int i = tid + it * 256;
            *(float4*)&yl[i >> 5][(i & 31) * 4] = s4[i];
        }
    }
    __syncthreads();

    const f32x4 Z4 = {0.f, 0.f, 0.f, 0.f};

    for (int step = 0; step < 2; ++step) {
        short8v yf[4];
        #pragma unroll
        for (int ck = 0; ck < 4; ++ck) yf[ck] = build_yfrag(yl, wv * 16 + q, ck, g);

        float m_run = NEGV, l_run = 0.f;
        f32x4 dacc[8];
        #pragma unroll
        for (int dt = 0; dt < 8; ++dt) dacc[dt] = Z4;

        for (int mc = 0; mc < 8; ++mc) {
            stage_K64(Kb + (size_t)mc * 64 * Dd, kl, tid);
            stage_VT(Vb + (size_t)mc * 64 * Dd, vt, tid);
            __syncthreads();

            f32x4 sc[4];
            #pragma unroll
            for (int mt = 0; mt < 4; ++mt) {
                f32x4 acc = Z4;
                #pragma unroll
                for (int ck = 0; ck < 4; ++ck)
                    acc = mfma16(read_kfrag(kl, mt, ck, g, q), yf[ck], acc);
                sc[mt] = acc;
            }
            unsigned au = (unsigned)(((mc < 4) ? mlo : mhi) >> ((mc & 3) * 16)) & 0xFFFFu;
            #pragma unroll
            for (int mt = 0; mt < 4; ++mt)
                #pragma unroll
                for (int r = 0; r < 4; ++r)
                    sc[mt][r] = ((au >> (mt * 4 + r)) & 1u) ? sc[mt][r] * itau : NEGV;
            float cm = NEGV;
            #pragma unroll
            for (int mt = 0; mt < 4; ++mt)
                #pragma unroll
                for (int r = 0; r < 4; ++r) cm = fmaxf(cm, sc[mt][r]);
            cm = fmaxf(cm, __shfl_xor(cm, 16));
            cm = fmaxf(cm, __shfl_xor(cm, 32));
            float mnew = fmaxf(m_run, cm);
            float corr = __expf(m_run - mnew);
            unsigned pw[8];
            float psum = 0.f;
            #pragma unroll
            for (int mt = 0; mt < 4; ++mt)
                #pragma unroll
                for (int r = 0; r < 4; r += 2) {
                    float e0 = __expf(sc[mt][r]     - mnew);
                    float e1 = __expf(sc[mt][r + 1] - mnew);
                    psum += e0 + e1;
                    pw[mt * 2 + (r >> 1)] = pack2bf(e0, e1);
                }
            psum += __shfl_xor(psum, 16);
            psum += __shfl_xor(psum, 32);
            l_run = l_run * corr + psum;
            m_run = mnew;
            float cr[4];
            #pragma unroll
            for (int r = 0; r < 4; ++r) cr[r] = __shfl(corr, 4 * g + r);
            #pragma unroll
            for (int dt = 0; dt < 8; ++dt)
                #pragma unroll
                for (int r = 0; r < 4; ++r) dacc[dt][r] *= cr[r];
            union { short8v s; uint4 u; } pa0, pa1;
            pa0.u = make_uint4(pw[0], pw[1], pw[2], pw[3]);
            pa1.u = make_uint4(pw[4], pw[5], pw[6], pw[7]);
            #pragma unroll
            for (int dt = 0; dt < 8; ++dt) {
                f32x4 acc = dacc[dt];
                acc = mfma16(pa0.s, read_vfrag(vt, 0, dt, g, q), acc);
                acc = mfma16(pa1.s, read_vfrag(vt, 1, dt, g, q), acc);
                dacc[dt] = acc;
            }
            __syncthreads();
        }
        float inv = (m_run != NEGV) ? 1.f / l_run : 0.f;
        float ivr[4];
        #pragma unroll
        for (int r = 0; r < 4; ++r) ivr[r] = __shfl(inv, 4 * g + r);
        #pragma unroll
        for (int r = 0; r < 4; ++r) {
            int row = wv * 16 + 4 * g + r;
            #pragma unroll
            for (int dt = 0; dt < 8; ++dt) {
                int d = dt * 16 + q;
                float del = dacc[dt][r] * ivr[r];
                float y0 = yl[row][d];
                float z = sw1[d] * y0 + sw2[d] * del + sgb[d];
                float gte = 1.f / (1.f + __expf(-z));
                yl[row][d] = y0 + gte * del;
            }
        }
        __syncthreads();
    }
    #pragma unroll
    for (int r16 = 0; r16 < 16; ++r16) {
        int n = n0 + wv * 16 + r16;
        float2 sv = *(const float2*)(seed + ((size_t)bs * Nn + n) * Dd + 2 * l);
        float2 ov;
        ov.x = yl[wv * 16 + r16][2 * l]     - sv.x;
        ov.y = yl[wv * 16 + r16][2 * l + 1] - sv.y;
        *(float2*)(y_em + (((size_t)bs * Nn + n) * Bb + b) * Dd + 2 * l) = ov;
    }
}

__global__ __launch_bounds__(256) void k2a_fb(
    const float* __restrict__ w_cand, const float* __restrict__ surprise,
    const float* __restrict__ emK, const float* __restrict__ emV, const float* __restrict__ emS,
    const float* __restrict__ rtau, const float* __restrict__ rtauw,
    float* __restrict__ delta_em, float* newV)
{
    const int bs = blockIdx.z, b = blockIdx.y, n0 = blockIdx.x * 64;
    const int tid = threadIdx.x;
    const int wv = tid >> 6, l = tid & 63, g = l >> 4, q = l & 15;

    __shared__ float yl[64][132];
    __shared__ ushort_t kl[64][136];
    __shared__ ushort_t vt[128][72];

    const float itau = 1.f / (softplusf(rtau[b]) + 0.1f);
    const float itw  = 1.f / (softplusf(rtauw[b]) + 0.1f);
    const size_t pair = (size_t)(bs * Bb + b);
    const float* Kb = emK + pair * (size_t)(Mm * Dd);
    const float* Vb = emV + pair * (size_t)(Mm * Dd);
    float* stats = newV + pair * (size_t)(Mm * Dd) + 448 * Dd;

    unsigned long long mlo, mhi;
    build_mask(emS, pair, g, mlo, mhi);
    {
        const float4* s4 = (const float4*)(w_cand + ((size_t)bs * Nn + n0) * Dd);
        #pragma unroll
        for (int it = 0; it < 8; ++it) {
            int i = tid + it * 256;
            *(float4*)&yl[i >> 5][(i & 31) * 4] = s4[i];
        }
    }
    __syncthreads();
    #pragma unroll
    for (int r = 0; r < 4; ++r) {
        int row = wv * 16 + 4 * g + r;
        float v8[8]; float p = 0.f;
        #pragma unroll
        for (int dt = 0; dt < 8; ++dt) { float v = yl[row][dt * 16 + q]; v8[dt] = v; p += v * v; }
        #pragma unroll
        for (int off = 1; off < 16; off <<= 1) p += __shfl_xor(p, off);
        float nrm = fmaxf(sqrtf(p), 1e-12f);
        float invn = 1.f / nrm;
        if (q == 0) stats[3072 + n0 + row] = nrm;
        #pragma unroll
        for (int dt = 0; dt < 8; ++dt) yl[row][dt * 16 + q] = v8[dt] * invn;
    }
    __syncthreads();

    const f32x4 Z4 = {0.f, 0.f, 0.f, 0.f};
    short8v yf[4];
    #pragma unroll
    for (int ck = 0; ck < 4; ++ck) yf[ck] = build_yfrag(yl, wv * 16 + q, ck, g);

    float m1 = NEGV, l1 = 0.f, m2 = NEGV, s2 = 0.f;
    f32x4 dacc[8];
    #pragma unroll
    for (int dt = 0; dt < 8; ++dt) dacc[dt] = Z4;

    for (int mc = 0; mc < 8; ++mc) {
        stage_K64(Kb + (size_t)mc * 64 * Dd, kl, tid);
        stage_VT(Vb + (size_t)mc * 64 * Dd, vt, tid);
        __syncthreads();

        f32x4 sc[4];
        #pragma unroll
        for (int mt = 0; mt < 4; ++mt) {
            f32x4 acc = Z4;
            #pragma unroll
            for (int ck = 0; ck < 4; ++ck)
                acc = mfma16(read_kfrag(kl, mt, ck, g, q), yf[ck], acc);
            sc[mt] = acc;
        }
        unsigned au = (unsigned)(((mc < 4) ? mlo : mhi) >> ((mc & 3) * 16)) & 0xFFFFu;

        float cm2 = NEGV;
        #pragma unroll
        for (int mt = 0; mt < 4; ++mt)
            #pragma unroll
            for (int r = 0; r < 4; ++r) {
                float v = ((au >> (mt * 4 + r)) & 1u) ? sc[mt][r] * itw : NEGV;
                cm2 = fmaxf(cm2, v);
            }
        cm2 = fmaxf(cm2, __shfl_xor(cm2, 16));
        cm2 = fmaxf(cm2, __shfl_xor(cm2, 32));
        float mn2 = fmaxf(m2, cm2);
        float c2 = __expf(m2 - mn2);
        float ps2 = 0.f;
        #pragma unroll
        for (int mt = 0; mt < 4; ++mt)
            #pragma unroll
            for (int r = 0; r < 4; ++r) {
                float v = ((au >> (mt * 4 + r)) & 1u) ? sc[mt][r] * itw : NEGV;
                ps2 += __expf(v - mn2);
            }
        ps2 += __shfl_xor(ps2, 16);
        ps2 += __shfl_xor(ps2, 32);
        s2 = s2 * c2 + ps2;
        m2 = mn2;

        #pragma unroll
        for (int mt = 0; mt < 4; ++mt)
            #pragma unroll
            for (int r = 0; r < 4; ++r)
                sc[mt][r] = ((au >> (mt * 4 + r)) & 1u) ? sc[mt][r] * itau : NEGV;
        float cm = NEGV;
        #pragma unroll
        for (int mt = 0; mt < 4; ++mt)
            #pragma unroll
            for (int r = 0; r < 4; ++r) cm = fmaxf(cm, sc[mt][r]);
        cm = fmaxf(cm, __shfl_xor(cm, 16));
        cm = fmaxf(cm, __shfl_xor(cm, 32));
        float mnew = fmaxf(m1, cm);
        float corr = __expf(m1 - mnew);
        unsigned pw[8];
        float psum = 0.f;
        #pragma unroll
        for (int mt = 0; mt < 4; ++mt)
            #pragma unroll
            for (int r = 0; r < 4; r += 2) {
                float e0 = __expf(sc[mt][r]     - mnew);
                float e1 = __expf(sc[mt][r + 1] - mnew);
                psum += e0 + e1;
                pw[mt * 2 + (r >> 1)] = pack2bf(e0, e1);
            }
        psum += __shfl_xor(psum, 16);
        psum += __shfl_xor(psum, 32);
        l1 = l1 * corr + psum;
        m1 = mnew;
        float cr[4];
        #pragma unroll
        for (int r = 0; r < 4; ++r) cr[r] = __shfl(corr, 4 * g + r);
        #pragma unroll
        for (int dt = 0; dt < 8; ++dt)
            #pragma unroll
            for (int r = 0; r < 4; ++r) dacc[dt][r] *= cr[r];
        union { short8v s; uint4 u; } pa0, pa1;
        pa0.u = make_uint4(pw[0], pw[1], pw[2], pw[3]);
        pa1.u = make_uint4(pw[4], pw[5], pw[6], pw[7]);
        #pragma unroll
        for (int dt = 0; dt < 8; ++dt) {
            f32x4 acc = dacc[dt];
            acc = mfma16(pa0.s, read_vfrag(vt, 0, dt, g, q), acc);
            acc = mfma16(pa1.s, read_vfrag(vt, 1, dt, g, q), acc);
            dacc[dt] = acc;
        }
        __syncthreads();
    }
    if (g == 0) {
        int n = n0 + wv * 16 + q;
        stats[1024 + n] = m2;
        stats[2048 + n] = s2;
    }
    float inv1 = (m1 != NEGV) ? 1.f / l1 : 0.f;
    float ivr[4];
    #pragma unroll
    for (int r = 0; r < 4; ++r) ivr[r] = __shfl(inv1, 4 * g + r);
    #pragma unroll
    for (int r = 0; r < 4; ++r) {
        int n = n0 + wv * 16 + 4 * g + r;
        const float* wcr = w_cand + ((size_t)bs * Nn + n) * Dd;
        const float* spr = surprise + ((size_t)bs * Nn + n) * Dd;
        float pe = 0.f, ps = 0.f, wcv[8];
        #pragma unroll
        for (int dt = 0; dt < 8; ++dt) {
            float wc = wcr[dt * 16 + q];
            float rec = dacc[dt][r] * ivr[r];
            float df = wc - rec;
            pe += df * df;
            float sv = spr[dt * 16 + q];
            ps += sv * sv;
            wcv[dt] = wc;
        }
        #pragma unroll
        for (int off = 1; off < 16; off <<= 1) {
            pe += __shfl_xor(pe, off);
            ps += __shfl_xor(ps, off);
        }
        float novl = 0.5f * sqrtf(ps) + 0.5f * sqrtf(pe);
        if (q == 0) stats[n] = novl;
        float* der = delta_em + (((size_t)bs * Nn + n) * Bb + b) * Dd;
        #pragma unroll
        for (int dt = 0; dt < 8; ++dt) der[dt * 16 + q] = novl * wcv[dt];
    }
}

__global__ __launch_bounds__(256) void k2b_fb(
    const float* __restrict__ w_cand, const float* __restrict__ emK, const float* __restrict__ emV,
    const float* __restrict__ emS, const float* __restrict__ emAge,
    const float* __restrict__ g_em, const float* __restrict__ rtauw,
    float* __restrict__ newK, float* newV,
    float* __restrict__ newAge, float* __restrict__ newS, int mt_base)
{
    const int bs = blockIdx.z, b = blockIdx.y, mt = mt_base + blockIdx.x;
    const int m0 = mt * 64;
    const int tid = threadIdx.x;
    const int wv = tid >> 6, l = tid & 63, g = l >> 4, q = l & 15;

    __shared__ ushort_t klw[64][136];
    __shared__ ushort_t vtw[128][72];
    __shared__ float sh_rm[Nn], sh_f[Nn], sh_fn[Nn], sh_inv[Nn];

    const float itw = 1.f / (softplusf(rtauw[b]) + 0.1f);
    const float gv = g_em[bs * Bb + b];
    const size_t pair = (size_t)(bs * Bb + b);
    const float* stats = newV + pair * (size_t)(Mm * Dd) + 448 * Dd;

    for (int i = tid; i < Nn; i += 256) {
        float nv = stats[i];
        float rm = stats[1024 + i];
        float rs = stats[2048 + i];
        float nr = stats[3072 + i];
        sh_rm[i] = rm;
        float f = nv / rs;
        sh_f[i]  = f;
        sh_fn[i] = f * nr;
        sh_inv[i] = 1.f / nr;
    }

    const int myM = m0 + wv * 16 + q;
    const float* Krow = emK + (pair * Mm + myM) * (size_t)Dd;
    short8v kf[4];
    #pragma unroll
    for (int ck = 0; ck < 4; ++ck) {
        float4 a = *(const float4*)(Krow + ck * 32 + g * 8);
        float4 c = *(const float4*)(Krow + ck * 32 + g * 8 + 4);
        union { short8v s; uint4 u; } r;
        r.u.x = pack2bf(a.x, a.y);
        r.u.y = pack2bf(a.z, a.w);
        r.u.z = pack2bf(c.x, c.y);
        r.u.w = pack2bf(c.z, c.w);
        kf[ck] = r.s;
    }
    const bool act = (emS[pair * Mm + myM] > 0.f);

    const f32x4 Z4 = {0.f, 0.f, 0.f, 0.f};
    f32x4 uKacc[8], uVacc[8];
    #pragma unroll
    for (int dt = 0; dt < 8; ++dt) { uKacc[dt] = Z4; uVacc[dt] = Z4; }
    float den = 0.f;

    __syncthreads();

    for (int nc = 0; nc < 16; ++nc) {
        const int nb = nc * 64;
        if (nc) __syncthreads();
        {
            const float4* s4 = (const float4*)(w_cand + ((size_t)bs * Nn + nb) * Dd);
            #pragma unroll
            for (int it = 0; it < 8; ++it) {
                int i = tid + it * 256;
                int m = i >> 5, c = i & 31;
                float4 v = s4[i];
                float inv = sh_inv[nb + m];
                uint2 w;
                w.x = pack2bf(v.x * inv, v.y * inv);
                w.y = pack2bf(v.z * inv, v.w * inv);
                *(uint2*)&klw[m][c * 4] = w;
            }
        }
        stage_WVT(w_cand + ((size_t)bs * Nn + nb) * Dd, sh_inv + nb, vtw, tid);
        __syncthreads();

        f32x4 sc[4];
        #pragma unroll
        for (int nt = 0; nt < 4; ++nt) {
            f32x4 acc = Z4;
            #pragma unroll
            for (int ck = 0; ck < 4; ++ck)
                acc = mfma16(read_kfrag(klw, nt, ck, g, q), kf[ck], acc);
            sc[nt] = acc;
        }
        unsigned pwK[8], pwV[8];
        #pragma unroll
        for (int nt = 0; nt < 4; ++nt) {
            float w0[4], w1[4];
            #pragma unroll
            for (int r = 0; r < 4; ++r) {
                int nl = nb + nt * 16 + 4 * g + r;
                float val = act ? sc[nt][r] * itw : NEGV;
                float E = __expf(val - sh_rm[nl]);
                float a = sh_f[nl] * E;
                w0[r] = a;
                w1[r] = sh_fn[nl] * E;
                den += a;
            }
            pwK[nt * 2 + 0] = pack2bf(w0[0], w0[1]);
            pwK[nt * 2 + 1] = pack2bf(w0[2], w0[3]);
            pwV[nt * 2 + 0] = pack2bf(w1[0], w1[1]);
            pwV[nt * 2 + 1] = pack2bf(w1[2], w1[3]);
        }
        union { short8v s; uint4 u; } paK0, paK1, paV0, paV1;
        paK0.u = make_uint4(pwK[0], pwK[1], pwK[2], pwK[3]);
        paK1.u = make_uint4(pwK[4], pwK[5], pwK[6], pwK[7]);
        paV0.u = make_uint4(pwV[0], pwV[1], pwV[2], pwV[3]);
        paV1.u = make_uint4(pwV[4], pwV[5], pwV[6], pwV[7]);
        #pragma unroll
        for (int dt = 0; dt < 8; ++dt) {
            short8v b0 = read_vfrag(vtw, 0, dt, g, q);
            short8v b1 = read_vfrag(vtw, 1, dt, g, q);
            uKacc[dt] = mfma16(paK0.s, b0, uKacc[dt]);
            uKacc[dt] = mfma16(paK1.s, b1, uKacc[dt]);
            uVacc[dt] = mfma16(paV0.s, b0, uVacc[dt]);
            uVacc[dt] = mfma16(paV1.s, b1, uVacc[dt]);
        }
    }

    den += __shfl_xor(den, 16);
    den += __shfl_xor(den, 32);
    float invd = 1.f / fmaxf(den, 1e-8f);
    float alpha = fminf(gv * den * (1.f / (float)Nn), 1.f);

    float pr[4] = {0.f, 0.f, 0.f, 0.f};
    #pragma unroll
    for (int dt = 0; dt < 8; ++dt)
        #pragma unroll
        for (int r = 0; r < 4; ++r) { float u = uKacc[dt][r]; pr[r] += u * u; }
    #pragma unroll
    for (int r = 0; r < 4; ++r) {
        #pragma unroll
        for (int off = 1; off < 16; off <<= 1) pr[r] += __shfl_xor(pr[r], off);
    }
    float alr[4], idr[4], inr[4];
    #pragma unroll
    for (int r = 0; r < 4; ++r) {
        alr[r] = __shfl(alpha, 4 * g + r);
        idr[r] = __shfl(invd,  4 * g + r);
        inr[r] = 1.f / fmaxf(sqrtf(pr[r]) * idr[r], 1e-12f);
    }
    #pragma unroll
    for (int r = 0; r < 4; ++r) {
        size_t rowoff = (pair * Mm + m0 + wv * 16 + 4 * g + r) * (size_t)Dd;
        float a = alr[r], om = 1.f - a, idv = idr[r], in = inr[r];
        #pragma unroll
        for (int dt = 0; dt < 8; ++dt) {
            int d = dt * 16 + q;
            float kv = emK[rowoff + d];
            float vv = emV[rowoff + d];
            newK[rowoff + d] = om * kv + a * uKacc[dt][r] * idv * in;
            newV[rowoff + d] = om * vv + a * uVacc[dt][r] * idv;
        }
    }
    if (q == 0) {
        #pragma unroll
        for (int r = 0; r < 4; ++r) {
            int m = m0 + wv * 16 + 4 * g + r;
            float a = alr[r];
            float S = emS[pair * Mm + m];
            newS[pair * Mm + m] = fminf(fmaxf(S + a, 0.f), 3.0f);
            newAge[pair * Mm + m] = emAge[pair * Mm + m] * (1.f - a);
        }
    }
}

// =====================================================================
// Kernel 2c: budget rescale of new_S in place (f32)
// =====================================================================
__global__ __launch_bounds__(256) void k2c_scale(float* newS)
{
    const int p = blockIdx.x, tid = threadIdx.x;
    __shared__ float red[256];
    float v0 = newS[(size_t)p * Mm + tid];
    float v1 = newS[(size_t)p * Mm + 256 + tid];
    red[tid] = v0 + v1;
    __syncthreads();
    for (int s = 128; s > 0; s >>= 1) {
        if (tid < s) red[tid] += red[tid + s];
        __syncthreads();
    }
    float tot = red[0];
    float sc = fminf(1.f, 32.0f / fmaxf(tot, 1e-8f));
    newS[(size_t)p * Mm + tid]       = v0 * sc;
    newS[(size_t)p * Mm + 256 + tid] = v1 * sc;
}

// =====================================================================
extern "C" void kernel_launch(void* const* d_in, const int* in_sizes, int n_in,
                              void* d_out, int out_size, void* d_ws, size_t ws_size,
                              hipStream_t stream)
{
    const float* seed     = (const float*)d_in[0];
    const float* w_cand   = (const float*)d_in[1];
    const float* surprise = (const float*)d_in[2];
    const float* g_em     = (const float*)d_in[3];
    const float* emK      = (const float*)d_in[4];
    const float* emV      = (const float*)d_in[5];
    const float* emS      = (const float*)d_in[6];
    const float* emAge    = (const float*)d_in[7];
    const float* w1       = (const float*)d_in[8];
    const float* w2       = (const float*)d_in[9];
    const float* gb       = (const float*)d_in[10];
    const float* rtau     = (const float*)d_in[11];
    const float* rtauw    = (const float*)d_in[12];

    float* out = (float*)d_out;
    float* y_em     = out;                            // (BS,N,B,D)  8388608
    float* delta_em = out + (size_t)8388608;          // (BS,N,B,D)  8388608
    float* newK     = out + (size_t)16777216;         // (BS,B,M,D)  4194304
    float* newV     = out + (size_t)20971520;         // (BS,B,M,D)  4194304
    float* newS     = out + (size_t)25165824;         // (BS,B,M)    32768
    float* newAge   = out + (size_t)25198592;         // (BS,B,M)    32768

    dim3 blk(256);

    // ws layout: Kbf 8.39MB | Vtb 8.39MB | wnr 2.10MB | wnT 2.10MB | nrm 32KB
    const size_t WS_NEED = 21004288;
    if (d_ws != nullptr && ws_size >= WS_NEED) {
        ushort_t* Kbf = (ushort_t*)d_ws;
        ushort_t* Vtb = Kbf + (size_t)64 * 65536;
        ushort_t* wnr = Vtb + (size_t)64 * 65536;
        ushort_t* wnT = wnr + (size_t)8 * 131072;
        float*    nrmb = (float*)(wnT + (size_t)8 * 131072);

        k0kv<<<dim3(512), blk, 0, stream>>>(emK, emV, Kbf, Vtb);
        k0w<<<dim3(128), blk, 0, stream>>>(w_cand, wnr, wnT, nrmb);
        k1_step<<<dim3(1024), blk, 0, stream>>>(seed, Kbf, Vtb, emS, w1, w2, gb, rtau, y_em, 0);
        k1_step<<<dim3(1024), blk, 0, stream>>>(seed, Kbf, Vtb, emS, w1, w2, gb, rtau, y_em, 1);
        k2a_pre<<<dim3(1024), blk, 0, stream>>>(w_cand, surprise, Kbf, Vtb, wnr, emS,
                                                rtau, rtauw, delta_em, newV);
        k2b_pre<<<dim3(448), blk, 0, stream>>>(wnr, wnT, Kbf, emK, emV, emS, emAge,
                                               g_em, rtauw, nrmb,
                                               newK, newV, newAge, newS, 0);
        k2b_pre<<<dim3(64), blk, 0, stream>>>(wnr, wnT, Kbf, emK, emV, emS, emAge,
                                              g_em, rtauw, nrmb,
                                              newK, newV, newAge, newS, 1);
    } else {
        dim3 g1(Nn / 64, Bb, BSz);
        k1_fb<<<g1, blk, 0, stream>>>(seed, emK, emV, emS, w1, w2, gb, rtau, y_em);
        k2a_fb<<<g1, blk, 0, stream>>>(w_cand, surprise, emK, emV, emS, rtau, rtauw,
                                       delta_em, newV);
        k2b_fb<<<dim3(7, Bb, BSz), blk, 0, stream>>>(w_cand, emK, emV, emS, emAge, g_em, rtauw,
                                                     newK, newV, newAge, newS, 0);
        k2b_fb<<<dim3(1, Bb, BSz), blk, 0, stream>>>(w_cand, emK, emV, emS, emAge, g_em, rtauw,
                                                     newK, newV, newAge, newS, 7);
    }
    k2c_scale<<<dim3(64), blk, 0, stream>>>(newS);
}

// Round 5
// 599.708 us; speedup vs baseline: 1.1880x; 1.1880x over previous
//
#include <hip/hip_runtime.h>
#include <cstddef>

#if __has_include(<hip/hip_bf16.h>)
#include <hip/hip_bf16.h>
#define HAVE_BF16_HDR 1
#endif

// ---------------- problem constants ----------------
constexpr int BSz = 8;     // batch
constexpr int Bb  = 8;     // blocks (episodic banks)
constexpr int Mm  = 512;   // memory slots
constexpr int Dd  = 128;   // feature dim
constexpr int Nn  = 1024;  // tokens
constexpr float NEGV = -1e30f;

typedef unsigned short ushort_t;
typedef __attribute__((ext_vector_type(8))) short short8v;  // 8 bf16 (4 VGPRs)
typedef __attribute__((ext_vector_type(4))) float f32x4;    // 4 fp32 acc

__device__ __forceinline__ float softplusf(float x) {
    return (x > 20.f) ? x : log1pf(expf(x));
}
// f32 -> bf16 RNE (manual; used when header path unavailable)
__device__ __forceinline__ unsigned short f2bf(float f) {
    unsigned u = __float_as_uint(f);
    u += 0x7fffu + ((u >> 16) & 1u);
    return (unsigned short)(u >> 16);
}
__device__ __forceinline__ unsigned pack2bf(float a, float b) {
#ifdef HAVE_BF16_HDR
    union { __hip_bfloat162 h; unsigned u; } cv;
    cv.h = __float22bfloat162_rn(make_float2(a, b));   // -> v_cvt_pk_bf16_f32
    return cv.u;
#else
    return (unsigned)f2bf(a) | ((unsigned)f2bf(b) << 16);
#endif
}
__device__ __forceinline__ f32x4 mfma16(short8v a, short8v b, f32x4 c) {
    return __builtin_amdgcn_mfma_f32_16x16x32_bf16(a, b, c, 0, 0, 0);
}

// ---- stage V chunk transposed: logical vt[d][m] = bf16(V[m][d]),
//      stored at column m ^ (((d>>2)&7)<<2) to break bank conflicts. ----
__device__ __forceinline__ void stage_VT(const float* __restrict__ src,
                                         ushort_t (*vt)[72], int tid) {
    const int wv = tid >> 6, l = tid & 63;
    const int c = l & 31, mh = l >> 5;         // mh in {0,1}
    #pragma unroll
    for (int it = 0; it < 8; ++it) {
        int pi = wv * 8 + it;                  // row-pair 0..31
        int m0 = pi * 2;
        float4 mine = *(const float4*)(src + (size_t)(m0 + mh) * Dd + c * 4);
        float4 oth;
        oth.x = __shfl_xor(mine.x, 32);
        oth.y = __shfl_xor(mine.y, 32);
        oth.z = __shfl_xor(mine.z, 32);
        oth.w = __shfl_xor(mine.w, 32);
        float a0 = mh ? oth.z  : mine.x;
        float a1 = mh ? mine.z : oth.x;
        float b0 = mh ? oth.w  : mine.y;
        float b1 = mh ? mine.w : oth.y;
        int d0 = c * 4 + mh * 2;
        int sw = ((d0 >> 2) & 7) << 2;
        int col = m0 ^ sw;
        *(unsigned*)&vt[d0][col]     = pack2bf(a0, a1);
        *(unsigned*)&vt[d0 + 1][col] = pack2bf(b0, b1);
    }
}

// ---- stage K chunk (fallback path) ----
__device__ __forceinline__ void stage_K64(const float* __restrict__ src,
                                          ushort_t (*kl)[136], int tid) {
    const float4* s4 = (const float4*)src;
    #pragma unroll
    for (int it = 0; it < 8; ++it) {
        int i = tid + it * 256;
        int m = i >> 5, c = i & 31;
        float4 v = s4[i];
        uint2 w;
        w.x = pack2bf(v.x, v.y);
        w.y = pack2bf(v.z, v.w);
        *(uint2*)&kl[m][c * 4] = w;
    }
}

// ---- stage w_norm chunk transposed with per-row scale (fallback k2b) ----
__device__ __forceinline__ void stage_WVT(const float* __restrict__ src,
                                          const float* sinv,
                                          ushort_t (*vt)[72], int tid) {
    const int wv = tid >> 6, l = tid & 63;
    const int c = l & 31, mh = l >> 5;
    #pragma unroll
    for (int it = 0; it < 8; ++it) {
        int pi = wv * 8 + it;
        int m0 = pi * 2;
        float inv = sinv[m0 + mh];
        float4 mine = *(const float4*)(src + (size_t)(m0 + mh) * Dd + c * 4);
        mine.x *= inv; mine.y *= inv; mine.z *= inv; mine.w *= inv;
        float4 oth;
        oth.x = __shfl_xor(mine.x, 32);
        oth.y = __shfl_xor(mine.y, 32);
        oth.z = __shfl_xor(mine.z, 32);
        oth.w = __shfl_xor(mine.w, 32);
        float a0 = mh ? oth.z  : mine.x;
        float a1 = mh ? mine.z : oth.x;
        float b0 = mh ? oth.w  : mine.y;
        float b1 = mh ? mine.w : oth.y;
        int d0 = c * 4 + mh * 2;
        int sw = ((d0 >> 2) & 7) << 2;
        int col = m0 ^ sw;
        *(unsigned*)&vt[d0][col]     = pack2bf(a0, a1);
        *(unsigned*)&vt[d0 + 1][col] = pack2bf(b0, b1);
    }
}

// ---- transpose normalized LDS rows into vt image (prep k0w) ----
__device__ __forceinline__ void transpose_yl_to_vt(const float (*yl)[132],
                                                   ushort_t (*vt)[72], int tid) {
    const int wv = tid >> 6, l = tid & 63;
    const int c = l & 31, mh = l >> 5;
    #pragma unroll
    for (int it = 0; it < 8; ++it) {
        int pi = wv * 8 + it;
        int m0 = pi * 2;
        float4 mine = *(const float4*)&yl[m0 + mh][c * 4];
        float4 oth;
        oth.x = __shfl_xor(mine.x, 32);
        oth.y = __shfl_xor(mine.y, 32);
        oth.z = __shfl_xor(mine.z, 32);
        oth.w = __shfl_xor(mine.w, 32);
        float a0 = mh ? oth.z  : mine.x;
        float a1 = mh ? mine.z : oth.x;
        float b0 = mh ? oth.w  : mine.y;
        float b1 = mh ? mine.w : oth.y;
        int d0 = c * 4 + mh * 2;
        int sw = ((d0 >> 2) & 7) << 2;
        int col = m0 ^ sw;
        *(unsigned*)&vt[d0][col]     = pack2bf(a0, a1);
        *(unsigned*)&vt[d0 + 1][col] = pack2bf(b0, b1);
    }
}

// ---- fragment readers ----
__device__ __forceinline__ short8v read_kfrag(const ushort_t (*kl)[136],
                                              int mt, int ck, int g, int q) {
    union { short8v s; uint4 u; } r;
    r.u = *(const uint4*)&kl[mt * 16 + q][ck * 32 + g * 8];
    return r.s;
}
__device__ __forceinline__ short8v build_yfrag(const float (*yl)[132], int row, int ck, int g) {
    float4 v0 = *(const float4*)&yl[row][ck * 32 + g * 8];
    float4 v1 = *(const float4*)&yl[row][ck * 32 + g * 8 + 4];
    union { short8v s; uint4 u; } r;
    r.u.x = pack2bf(v0.x, v0.y);
    r.u.y = pack2bf(v0.z, v0.w);
    r.u.z = pack2bf(v1.x, v1.y);
    r.u.w = pack2bf(v1.z, v1.w);
    return r.s;
}
__device__ __forceinline__ short8v build_gfrag(const float* __restrict__ yr, int ck, int g) {
    float4 a = *(const float4*)(yr + ck * 32 + g * 8);
    float4 c = *(const float4*)(yr + ck * 32 + g * 8 + 4);
    union { short8v s; uint4 u; } r;
    r.u.x = pack2bf(a.x, a.y);
    r.u.y = pack2bf(a.z, a.w);
    r.u.z = pack2bf(c.x, c.y);
    r.u.w = pack2bf(c.z, c.w);
    return r.s;
}
__device__ __forceinline__ short8v read_vfrag(const ushort_t (*vt)[72],
                                              int kc, int dt, int g, int q) {
    int d = dt * 16 + q;
    int sw = ((d >> 2) & 7) << 2;
    uint2 lo = *(const uint2*)&vt[d][(kc * 32 + 4 * g) ^ sw];
    uint2 hi = *(const uint2*)&vt[d][(kc * 32 + 16 + 4 * g) ^ sw];
    union { short8v s; uint4 u; } r;
    r.u.x = lo.x; r.u.y = lo.y; r.u.z = hi.x; r.u.w = hi.y;
    return r.s;
}

// ---- LDS tile writes from prefetched registers (pre path) ----
__device__ __forceinline__ void kwrite(ushort_t (*kl)[136], const uint4* pf, int tid) {
    #pragma unroll
    for (int j = 0; j < 4; ++j) {
        int i = tid + j * 256;
        *(uint4*)&kl[i >> 4][(i & 15) * 8] = pf[j];
    }
}
__device__ __forceinline__ void vwrite(ushort_t (*vt)[72], const uint4* pf, int tid) {
    #pragma unroll
    for (int j = 0; j < 4; ++j) {
        int i = tid + j * 256;
        *(uint4*)&vt[i >> 3][(i & 7) * 8] = pf[j];
    }
}

// ---- activity-mask builder ----
__device__ __forceinline__ void build_mask(const float* __restrict__ emS, size_t pair,
                                           int g, unsigned long long& mlo,
                                           unsigned long long& mhi) {
    mlo = 0ull; mhi = 0ull;
    const float4* sp = (const float4*)(emS + pair * Mm);
    #pragma unroll 8
    for (int t = 0; t < 32; ++t) {
        float4 s = sp[t * 4 + g];
        unsigned long long bits = (s.x > 0.f ? 1ull : 0ull) | (s.y > 0.f ? 2ull : 0ull)
                                | (s.z > 0.f ? 4ull : 0ull) | (s.w > 0.f ? 8ull : 0ull);
        if (t < 16) mlo |= bits << (t * 4);
        else        mhi |= bits << ((t - 16) * 4);
    }
}

// =====================================================================
// Prep kernel k0kv: emK -> bf16 row image; emV -> bf16 transposed image.
// =====================================================================
__global__ __launch_bounds__(256) void k0kv(
    const float* __restrict__ emK, const float* __restrict__ emV,
    ushort_t* __restrict__ Kbf, ushort_t* __restrict__ Vtb)
{
    const int id = blockIdx.x;
    const int b = id & 7, t = id >> 3, mc = t & 7, bs = t >> 3;
    const int tid = threadIdx.x;
    const size_t pair = (size_t)(bs * Bb + b);
    __shared__ ushort_t vt[128][72];
    {
        const float4* s4 = (const float4*)(emK + (pair * Mm + (size_t)mc * 64) * Dd);
        uint2* dst = (uint2*)(Kbf + pair * 65536u + (size_t)mc * 8192u);
        #pragma unroll
        for (int it = 0; it < 8; ++it) {
            int i = tid + it * 256;
            float4 v = s4[i];
            uint2 w;
            w.x = pack2bf(v.x, v.y);
            w.y = pack2bf(v.z, v.w);
            dst[i] = w;
        }
    }
    stage_VT(emV + (pair * Mm + (size_t)mc * 64) * Dd, vt, tid);
    __syncthreads();
    {
        uint4* dst = (uint4*)(Vtb + pair * 65536u + (size_t)mc * 8192u);
        #pragma unroll
        for (int it = 0; it < 4; ++it) {
            int i = tid + it * 256;
            dst[i] = *(const uint4*)&vt[i >> 3][(i & 7) * 8];
        }
    }
}

// =====================================================================
// Prep kernel k0w: w_cand -> w_norm bf16 row image + transposed image + nrm
// =====================================================================
__global__ __launch_bounds__(256) void k0w(
    const float* __restrict__ w_cand, ushort_t* __restrict__ wnr,
    ushort_t* __restrict__ wnT, float* __restrict__ nrmb)
{
    const int id = blockIdx.x;
    const int bs = id & 7, nb = (id >> 3) * 64;
    const int tid = threadIdx.x;
    const int wv = tid >> 6, l = tid & 63, g = l >> 4, q = l & 15;
    __shared__ float yl[64][132];
    __shared__ ushort_t vt[128][72];
    {
        const float4* s4 = (const float4*)(w_cand + ((size_t)bs * Nn + nb) * Dd);
        #pragma unroll
        for (int it = 0; it < 8; ++it) {
            int i = tid + it * 256;
            *(float4*)&yl[i >> 5][(i & 31) * 4] = s4[i];
        }
    }
    __syncthreads();
    #pragma unroll
    for (int r = 0; r < 4; ++r) {
        int row = wv * 16 + 4 * g + r;
        float v8[8]; float p = 0.f;
        #pragma unroll
        for (int dt = 0; dt < 8; ++dt) { float v = yl[row][dt * 16 + q]; v8[dt] = v; p += v * v; }
        #pragma unroll
        for (int off = 1; off < 16; off <<= 1) p += __shfl_xor(p, off);
        float nrm = fmaxf(sqrtf(p), 1e-12f);
        float inv = 1.f / nrm;
        if (q == 0) nrmb[(size_t)bs * Nn + nb + row] = nrm;
        #pragma unroll
        for (int dt = 0; dt < 8; ++dt) yl[row][dt * 16 + q] = v8[dt] * inv;
    }
    __syncthreads();
    {
        uint4* dst = (uint4*)(wnr + (size_t)bs * 131072u) + (size_t)nb * 16u;
        #pragma unroll
        for (int j = 0; j < 4; ++j) {
            int i = tid + j * 256;
            int row = i >> 4, c8 = i & 15;
            float4 a = *(const float4*)&yl[row][c8 * 8];
            float4 c = *(const float4*)&yl[row][c8 * 8 + 4];
            uint4 w;
            w.x = pack2bf(a.x, a.y); w.y = pack2bf(a.z, a.w);
            w.z = pack2bf(c.x, c.y); w.w = pack2bf(c.z, c.w);
            dst[i] = w;
        }
    }
    transpose_yl_to_vt(yl, vt, tid);
    __syncthreads();
    {
        uint4* dst = (uint4*)(wnT + (size_t)bs * 131072u) + (size_t)(nb >> 6) * 1024u;
        #pragma unroll
        for (int it = 0; it < 4; ++it) {
            int i = tid + it * 256;
            dst[i] = *(const uint4*)&vt[i >> 3][(i & 7) * 8];
        }
    }
}

// =====================================================================
// Kernel 1 (monolithic): both attention steps in one dispatch.
// LDS union: yl f32[64][132] aliases kl+vt (used only for the inter-step
// wave transpose). y after step 0 is also written to y_em (L2-warm) and
// re-read for the step-1 gate. #pragma unroll 1 keeps the body I-cache
// resident. 1D grid 1024; swizzle b = id&7.
// =====================================================================
__global__ __launch_bounds__(256) void k1_mono(
    const float* __restrict__ seed, const ushort_t* __restrict__ Kbf,
    const ushort_t* __restrict__ Vtb, const float* __restrict__ emS,
    const float* __restrict__ w1, const float* __restrict__ w2,
    const float* __restrict__ gb, const float* __restrict__ rtau,
    float* __restrict__ y_em)
{
    const int id = blockIdx.x;
    const int b = id & 7, bs = id >> 7, n0 = ((id >> 3) & 15) << 6;
    const int tid = threadIdx.x;
    const int wv = tid >> 6, l = tid & 63, g = l >> 4, q = l & 15;

    __shared__ __align__(16) unsigned char smem[35840];   // kl 17408 + vt 18432
    ushort_t (*kl)[136] = (ushort_t (*)[136])smem;
    ushort_t (*vt)[72]  = (ushort_t (*)[72])(smem + 17408);
    float    (*yl)[132] = (float (*)[132])smem;           // alias (33792 B)
    __shared__ float sw1[Dd], sw2[Dd], sgb[Dd];

    const float itau = 1.f / (softplusf(rtau[b]) + 0.1f);
    const size_t pair = (size_t)(bs * Bb + b);
    const uint4* Ksrc = (const uint4*)(Kbf + pair * 65536u);
    const uint4* Vsrc = (const uint4*)(Vtb + pair * 65536u);

    if (tid < Dd) {
        sw1[tid] = w1[b * Dd + tid];
        sw2[tid] = w2[b * Dd + tid];
        sgb[tid] = gb[b * Dd + tid];
    }
    unsigned long long mlo, mhi;
    build_mask(emS, pair, g, mlo, mhi);

    // y B-frags from seed (lane-local row n = n0 + wv*16 + q)
    short8v yf[4];
    {
        const float* yr = seed + ((size_t)bs * Nn + n0 + wv * 16 + q) * Dd;
        #pragma unroll
        for (int ck = 0; ck < 4; ++ck) yf[ck] = build_gfrag(yr, ck, g);
    }
    uint4 kpf[4], vpf[4];
    #pragma unroll
    for (int j = 0; j < 4; ++j) { kpf[j] = Ksrc[tid + j * 256]; vpf[j] = Vsrc[tid + j * 256]; }

    const f32x4 Z4 = {0.f, 0.f, 0.f, 0.f};

    #pragma unroll 1
    for (int step = 0; step < 2; ++step) {
        float m_run = NEGV, l_run = 0.f;
        f32x4 dacc[8];
        #pragma unroll
        for (int dt = 0; dt < 8; ++dt) dacc[dt] = Z4;

        #pragma unroll 1
        for (int mc = 0; mc < 8; ++mc) {
            kwrite(kl, kpf, tid);
            vwrite(vt, vpf, tid);
            __syncthreads();
            if (!(step == 1 && mc == 7)) {   // T14: next chunk in flight under compute
                int nx = (mc < 7) ? mc + 1 : 0;
                #pragma unroll
                for (int j = 0; j < 4; ++j) {
                    kpf[j] = Ksrc[nx * 1024 + tid + j * 256];
                    vpf[j] = Vsrc[nx * 1024 + tid + j * 256];
                }
            }

            f32x4 sc[4];
            #pragma unroll
            for (int mt = 0; mt < 4; ++mt) {
                f32x4 acc = Z4;
                #pragma unroll
                for (int ck = 0; ck < 4; ++ck)
                    acc = mfma16(read_kfrag(kl, mt, ck, g, q), yf[ck], acc);
                sc[mt] = acc;
            }
            unsigned au = (unsigned)(((mc < 4) ? mlo : mhi) >> ((mc & 3) * 16)) & 0xFFFFu;
            #pragma unroll
            for (int mt = 0; mt < 4; ++mt)
                #pragma unroll
                for (int r = 0; r < 4; ++r)
                    sc[mt][r] = ((au >> (mt * 4 + r)) & 1u) ? sc[mt][r] * itau : NEGV;
            float cm = NEGV;
            #pragma unroll
            for (int mt = 0; mt < 4; ++mt)
                #pragma unroll
                for (int r = 0; r < 4; ++r) cm = fmaxf(cm, sc[mt][r]);
            cm = fmaxf(cm, __shfl_xor(cm, 16));
            cm = fmaxf(cm, __shfl_xor(cm, 32));
            float mnew = fmaxf(m_run, cm);
            float corr = __expf(m_run - mnew);
            unsigned pw[8];
            float psum = 0.f;
            #pragma unroll
            for (int mt = 0; mt < 4; ++mt)
                #pragma unroll
                for (int r = 0; r < 4; r += 2) {
                    float e0 = __expf(sc[mt][r]     - mnew);
                    float e1 = __expf(sc[mt][r + 1] - mnew);
                    psum += e0 + e1;
                    pw[mt * 2 + (r >> 1)] = pack2bf(e0, e1);
                }
            psum += __shfl_xor(psum, 16);
            psum += __shfl_xor(psum, 32);
            l_run = l_run * corr + psum;
            m_run = mnew;
            float cr[4];
            #pragma unroll
            for (int r = 0; r < 4; ++r) cr[r] = __shfl(corr, 4 * g + r);
            #pragma unroll
            for (int dt = 0; dt < 8; ++dt)
                #pragma unroll
                for (int r = 0; r < 4; ++r) dacc[dt][r] *= cr[r];
            union { short8v s; uint4 u; } pa0, pa1;
            pa0.u = make_uint4(pw[0], pw[1], pw[2], pw[3]);
            pa1.u = make_uint4(pw[4], pw[5], pw[6], pw[7]);
            #pragma unroll
            for (int dt = 0; dt < 8; ++dt) {
                f32x4 acc = dacc[dt];
                acc = mfma16(pa0.s, read_vfrag(vt, 0, dt, g, q), acc);
                acc = mfma16(pa1.s, read_vfrag(vt, 1, dt, g, q), acc);
                dacc[dt] = acc;
            }
            __syncthreads();
        }
        // ---- finalize + gate (rows wv*16+4g+r, cols dt*16+q) ----
        float inv = (m_run != NEGV) ? 1.f / l_run : 0.f;
        float ivr[4];
        #pragma unroll
        for (int r = 0; r < 4; ++r) ivr[r] = __shfl(inv, 4 * g + r);

        if (step == 0) {
            #pragma unroll
            for (int r = 0; r < 4; ++r) {
                int n = n0 + wv * 16 + 4 * g + r;
                const float* sr = seed + ((size_t)bs * Nn + n) * Dd;
                float* yo = y_em + (((size_t)bs * Nn + n) * Bb + b) * Dd;
                int row = wv * 16 + 4 * g + r;
                #pragma unroll
                for (int dt = 0; dt < 8; ++dt) {
                    int d = dt * 16 + q;
                    float y0 = sr[d];
                    float del = dacc[dt][r] * ivr[r];
                    float z = sw1[d] * y0 + sw2[d] * del + sgb[d];
                    float gte = 1.f / (1.f + __expf(-z));
                    float yn = y0 + gte * del;
                    yl[row][d] = yn;     // for the in-LDS transpose
                    yo[d] = yn;          // L2-warm copy for step-1 gate
                }
            }
            __syncthreads();
            {
                const int row = wv * 16 + q;
                #pragma unroll
                for (int ck = 0; ck < 4; ++ck) yf[ck] = build_yfrag(yl, row, ck, g);
            }
            __syncthreads();   // before step-1 kwrite clobbers the alias
        } else {
            #pragma unroll
            for (int r = 0; r < 4; ++r) {
                int n = n0 + wv * 16 + 4 * g + r;
                const float* sr = seed + ((size_t)bs * Nn + n) * Dd;
                float* yo = y_em + (((size_t)bs * Nn + n) * Bb + b) * Dd;
                #pragma unroll
                for (int dt = 0; dt < 8; ++dt) {
                    int d = dt * 16 + q;
                    float y0 = yo[d];                    // step-0 result (L2)
                    float del = dacc[dt][r] * ivr[r];
                    float z = sw1[d] * y0 + sw2[d] * del + sgb[d];
                    float gte = 1.f / (1.f + __expf(-z));
                    yo[d] = y0 + gte * del - sr[d];
                }
            }
        }
    }
}

// =====================================================================
// Kernel 2a (pre): novelty path, swizzled 1D grid (XCD == b)
// =====================================================================
__global__ __launch_bounds__(256) void k2a_pre(
    const float* __restrict__ w_cand, const float* __restrict__ surprise,
    const ushort_t* __restrict__ Kbf, const ushort_t* __restrict__ Vtb,
    const ushort_t* __restrict__ wnr, const float* __restrict__ emS,
    const float* __restrict__ rtau, const float* __restrict__ rtauw,
    float* __restrict__ delta_em, float* newV /* stats alias */)
{
    const int id = blockIdx.x;
    const int b = id & 7, bs = id >> 7, n0 = ((id >> 3) & 15) << 6;
    const int tid = threadIdx.x;
    const int wv = tid >> 6, l = tid & 63, g = l >> 4, q = l & 15;

    __shared__ ushort_t kl[64][136];
    __shared__ ushort_t vt[128][72];

    const float itau = 1.f / (softplusf(rtau[b]) + 0.1f);
    const float itw  = 1.f / (softplusf(rtauw[b]) + 0.1f);
    const size_t pair = (size_t)(bs * Bb + b);
    const uint4* Ksrc = (const uint4*)(Kbf + pair * 65536u);
    const uint4* Vsrc = (const uint4*)(Vtb + pair * 65536u);
    float* stats = newV + pair * (size_t)(Mm * Dd) + 448 * Dd;

    unsigned long long mlo, mhi;
    build_mask(emS, pair, g, mlo, mhi);

    short8v yf[4];
    {
        const uint4* wr = (const uint4*)(wnr + (size_t)bs * 131072u
                                         + (size_t)(n0 + wv * 16 + q) * 128u);
        #pragma unroll
        for (int ck = 0; ck < 4; ++ck) {
            union { short8v s; uint4 u; } r;
            r.u = wr[ck * 4 + g];
            yf[ck] = r.s;
        }
    }
    uint4 kpf[4], vpf[4];
    #pragma unroll
    for (int j = 0; j < 4; ++j) { kpf[j] = Ksrc[tid + j * 256]; vpf[j] = Vsrc[tid + j * 256]; }

    const f32x4 Z4 = {0.f, 0.f, 0.f, 0.f};
    float m1 = NEGV, l1 = 0.f, m2 = NEGV, s2 = 0.f;
    f32x4 dacc[8];
    #pragma unroll
    for (int dt = 0; dt < 8; ++dt) dacc[dt] = Z4;

    #pragma unroll 1
    for (int mc = 0; mc < 8; ++mc) {
        kwrite(kl, kpf, tid);
        vwrite(vt, vpf, tid);
        __syncthreads();
        if (mc < 7) {
            #pragma unroll
            for (int j = 0; j < 4; ++j) {
                kpf[j] = Ksrc[(mc + 1) * 1024 + tid + j * 256];
                vpf[j] = Vsrc[(mc + 1) * 1024 + tid + j * 256];
            }
        }

        f32x4 sc[4];   // RAW dots
        #pragma unroll
        for (int mt = 0; mt < 4; ++mt) {
            f32x4 acc = Z4;
            #pragma unroll
            for (int ck = 0; ck < 4; ++ck)
                acc = mfma16(read_kfrag(kl, mt, ck, g, q), yf[ck], acc);
            sc[mt] = acc;
        }
        unsigned au = (unsigned)(((mc < 4) ? mlo : mhi) >> ((mc & 3) * 16)) & 0xFFFFu;

        float cm2 = NEGV;
        #pragma unroll
        for (int mt = 0; mt < 4; ++mt)
            #pragma unroll
            for (int r = 0; r < 4; ++r) {
                float v = ((au >> (mt * 4 + r)) & 1u) ? sc[mt][r] * itw : NEGV;
                cm2 = fmaxf(cm2, v);
            }
        cm2 = fmaxf(cm2, __shfl_xor(cm2, 16));
        cm2 = fmaxf(cm2, __shfl_xor(cm2, 32));
        float mn2 = fmaxf(m2, cm2);
        float c2 = __expf(m2 - mn2);
        float ps2 = 0.f;
        #pragma unroll
        for (int mt = 0; mt < 4; ++mt)
            #pragma unroll
            for (int r = 0; r < 4; ++r) {
                float v = ((au >> (mt * 4 + r)) & 1u) ? sc[mt][r] * itw : NEGV;
                ps2 += __expf(v - mn2);
            }
        ps2 += __shfl_xor(ps2, 16);
        ps2 += __shfl_xor(ps2, 32);
        s2 = s2 * c2 + ps2;
        m2 = mn2;

        #pragma unroll
        for (int mt = 0; mt < 4; ++mt)
            #pragma unroll
            for (int r = 0; r < 4; ++r)
                sc[mt][r] = ((au >> (mt * 4 + r)) & 1u) ? sc[mt][r] * itau : NEGV;
        float cm = NEGV;
        #pragma unroll
        for (int mt = 0; mt < 4; ++mt)
            #pragma unroll
            for (int r = 0; r < 4; ++r) cm = fmaxf(cm, sc[mt][r]);
        cm = fmaxf(cm, __shfl_xor(cm, 16));
        cm = fmaxf(cm, __shfl_xor(cm, 32));
        float mnew = fmaxf(m1, cm);
        float corr = __expf(m1 - mnew);
        unsigned pw[8];
        float psum = 0.f;
        #pragma unroll
        for (int mt = 0; mt < 4; ++mt)
            #pragma unroll
            for (int r = 0; r < 4; r += 2) {
                float e0 = __expf(sc[mt][r]     - mnew);
                float e1 = __expf(sc[mt][r + 1] - mnew);
                psum += e0 + e1;
                pw[mt * 2 + (r >> 1)] = pack2bf(e0, e1);
            }
        psum += __shfl_xor(psum, 16);
        psum += __shfl_xor(psum, 32);
        l1 = l1 * corr + psum;
        m1 = mnew;
        float cr[4];
        #pragma unroll
        for (int r = 0; r < 4; ++r) cr[r] = __shfl(corr, 4 * g + r);
        #pragma unroll
        for (int dt = 0; dt < 8; ++dt)
            #pragma unroll
            for (int r = 0; r < 4; ++r) dacc[dt][r] *= cr[r];
        union { short8v s; uint4 u; } pa0, pa1;
        pa0.u = make_uint4(pw[0], pw[1], pw[2], pw[3]);
        pa1.u = make_uint4(pw[4], pw[5], pw[6], pw[7]);
        #pragma unroll
        for (int dt = 0; dt < 8; ++dt) {
            f32x4 acc = dacc[dt];
            acc = mfma16(pa0.s, read_vfrag(vt, 0, dt, g, q), acc);
            acc = mfma16(pa1.s, read_vfrag(vt, 1, dt, g, q), acc);
            dacc[dt] = acc;
        }
        __syncthreads();
    }
    if (g == 0) {
        int n = n0 + wv * 16 + q;
        stats[1024 + n] = m2;
        stats[2048 + n] = s2;
    }
    float inv1 = (m1 != NEGV) ? 1.f / l1 : 0.f;
    float ivr[4];
    #pragma unroll
    for (int r = 0; r < 4; ++r) ivr[r] = __shfl(inv1, 4 * g + r);
    #pragma unroll
    for (int r = 0; r < 4; ++r) {
        int n = n0 + wv * 16 + 4 * g + r;
        const float* wcr = w_cand + ((size_t)bs * Nn + n) * Dd;
        const float* spr = surprise + ((size_t)bs * Nn + n) * Dd;
        float pe = 0.f, ps = 0.f, wcv[8];
        #pragma unroll
        for (int dt = 0; dt < 8; ++dt) {
            float wc = wcr[dt * 16 + q];
            float rec = dacc[dt][r] * ivr[r];
            float df = wc - rec;
            pe += df * df;
            float sv = spr[dt * 16 + q];
            ps += sv * sv;
            wcv[dt] = wc;
        }
        #pragma unroll
        for (int off = 1; off < 16; off <<= 1) {
            pe += __shfl_xor(pe, off);
            ps += __shfl_xor(ps, off);
        }
        float novl = 0.5f * sqrtf(ps) + 0.5f * sqrtf(pe);
        if (q == 0) stats[n] = novl;
        float* der = delta_em + (((size_t)bs * Nn + n) * Bb + b) * Dd;
        #pragma unroll
        for (int dt = 0; dt < 8; ++dt) der[dt * 16 + q] = novl * wcv[dt];
    }
}

// =====================================================================
// Kernel 2b (pre): route recompute + updates; swizzled 1D grid (XCD==bs).
// =====================================================================
__global__ __launch_bounds__(256) void k2b_pre(
    const ushort_t* __restrict__ wnr, const ushort_t* __restrict__ wnT,
    const ushort_t* __restrict__ Kbf,
    const float* __restrict__ emK, const float* __restrict__ emV,
    const float* __restrict__ emS, const float* __restrict__ emAge,
    const float* __restrict__ g_em, const float* __restrict__ rtauw,
    const float* __restrict__ nrmb,
    float* __restrict__ newK, float* newV /* aliases stats */,
    float* __restrict__ newAge, float* __restrict__ newS, int phase)
{
    const int id = blockIdx.x;
    const int bs = id & 7;
    const int t = id >> 3;
    const int b  = phase ? t : t / 7;
    const int mt = phase ? 7 : t % 7;
    const int m0 = mt * 64;
    const int tid = threadIdx.x;
    const int wv = tid >> 6, l = tid & 63, g = l >> 4, q = l & 15;

    __shared__ ushort_t klw[64][136];
    __shared__ ushort_t vtw[128][72];
    __shared__ float sh_rm[Nn], sh_f[Nn], sh_fn[Nn];

    const float itw = 1.f / (softplusf(rtauw[b]) + 0.1f);
    const float gv = g_em[bs * Bb + b];
    const size_t pair = (size_t)(bs * Bb + b);
    const float* stats = newV + pair * (size_t)(Mm * Dd) + 448 * Dd;

    for (int i = tid; i < Nn; i += 256) {
        float nv = stats[i];
        float rm = stats[1024 + i];
        float rs = stats[2048 + i];
        float nr = nrmb[(size_t)bs * Nn + i];
        sh_rm[i] = rm;
        float f = nv / rs;
        sh_f[i]  = f;
        sh_fn[i] = f * nr;
    }

    const int myM = m0 + wv * 16 + q;
    short8v kf[4];
    {
        const uint4* kr = (const uint4*)(Kbf + pair * 65536u + (size_t)myM * 128u);
        #pragma unroll
        for (int ck = 0; ck < 4; ++ck) {
            union { short8v s; uint4 u; } r;
            r.u = kr[ck * 4 + g];
            kf[ck] = r.s;
        }
    }
    const bool act = (emS[pair * Mm + myM] > 0.f);

    const uint4* Wr = (const uint4*)(wnr + (size_t)bs * 131072u);
    const uint4* Wt = (const uint4*)(wnT + (size_t)bs * 131072u);
    uint4 wpf[4], tpf[4];
    #pragma unroll
    for (int j = 0; j < 4; ++j) { wpf[j] = Wr[tid + j * 256]; tpf[j] = Wt[tid + j * 256]; }

    const f32x4 Z4 = {0.f, 0.f, 0.f, 0.f};
    f32x4 uKacc[8], uVacc[8];
    #pragma unroll
    for (int dt = 0; dt < 8; ++dt) { uKacc[dt] = Z4; uVacc[dt] = Z4; }
    float den = 0.f;

    #pragma unroll 1
    for (int nc = 0; nc < 16; ++nc) {
        const int nb = nc * 64;
        kwrite(klw, wpf, tid);
        vwrite(vtw, tpf, tid);
        __syncthreads();
        if (nc < 15) {
            #pragma unroll
            for (int j = 0; j < 4; ++j) {
                wpf[j] = Wr[(nc + 1) * 1024 + tid + j * 256];
                tpf[j] = Wt[(nc + 1) * 1024 + tid + j * 256];
            }
        }

        f32x4 sc[4];
        #pragma unroll
        for (int nt = 0; nt < 4; ++nt) {
            f32x4 acc = Z4;
            #pragma unroll
            for (int ck = 0; ck < 4; ++ck)
                acc = mfma16(read_kfrag(klw, nt, ck, g, q), kf[ck], acc);
            sc[nt] = acc;
        }
        unsigned pwK[8], pwV[8];
        #pragma unroll
        for (int nt = 0; nt < 4; ++nt) {
            float w0[4], w1[4];
            #pragma unroll
            for (int r = 0; r < 4; ++r) {
                int nl = nb + nt * 16 + 4 * g + r;
                float val = act ? sc[nt][r] * itw : NEGV;
                float E = __expf(val - sh_rm[nl]);
                float a = sh_f[nl] * E;
                w0[r] = a;
                w1[r] = sh_fn[nl] * E;
                den += a;
            }
            pwK[nt * 2 + 0] = pack2bf(w0[0], w0[1]);
            pwK[nt * 2 + 1] = pack2bf(w0[2], w0[3]);
            pwV[nt * 2 + 0] = pack2bf(w1[0], w1[1]);
            pwV[nt * 2 + 1] = pack2bf(w1[2], w1[3]);
        }
        union { short8v s; uint4 u; } paK0, paK1, paV0, paV1;
        paK0.u = make_uint4(pwK[0], pwK[1], pwK[2], pwK[3]);
        paK1.u = make_uint4(pwK[4], pwK[5], pwK[6], pwK[7]);
        paV0.u = make_uint4(pwV[0], pwV[1], pwV[2], pwV[3]);
        paV1.u = make_uint4(pwV[4], pwV[5], pwV[6], pwV[7]);
        #pragma unroll
        for (int dt = 0; dt < 8; ++dt) {
            short8v b0 = read_vfrag(vtw, 0, dt, g, q);
            short8v b1 = read_vfrag(vtw, 1, dt, g, q);
            uKacc[dt] = mfma16(paK0.s, b0, uKacc[dt]);
            uKacc[dt] = mfma16(paK1.s, b1, uKacc[dt]);
            uVacc[dt] = mfma16(paV0.s, b0, uVacc[dt]);
            uVacc[dt] = mfma16(paV1.s, b1, uVacc[dt]);
        }
        __syncthreads();
    }

    // ---- epilogue ----
    den += __shfl_xor(den, 16);
    den += __shfl_xor(den, 32);
    float invd = 1.f / fmaxf(den, 1e-8f);
    float alpha = fminf(gv * den * (1.f / (float)Nn), 1.f);

    float pr[4] = {0.f, 0.f, 0.f, 0.f};
    #pragma unroll
    for (int dt = 0; dt < 8; ++dt)
        #pragma unroll
        for (int r = 0; r < 4; ++r) { float u = uKacc[dt][r]; pr[r] += u * u; }
    #pragma unroll
    for (int r = 0; r < 4; ++r) {
        #pragma unroll
        for (int off = 1; off < 16; off <<= 1) pr[r] += __shfl_xor(pr[r], off);
    }
    float alr[4], idr[4], inr[4];
    #pragma unroll
    for (int r = 0; r < 4; ++r) {
        alr[r] = __shfl(alpha, 4 * g + r);
        idr[r] = __shfl(invd,  4 * g + r);
        inr[r] = 1.f / fmaxf(sqrtf(pr[r]) * idr[r], 1e-12f);
    }
    #pragma unroll
    for (int r = 0; r < 4; ++r) {
        size_t rowoff = (pair * Mm + m0 + wv * 16 + 4 * g + r) * (size_t)Dd;
        float a = alr[r], om = 1.f - a, idv = idr[r], in = inr[r];
        #pragma unroll
        for (int dt = 0; dt < 8; ++dt) {
            int d = dt * 16 + q;
            float kv = emK[rowoff + d];
            float vv = emV[rowoff + d];
            newK[rowoff + d] = om * kv + a * uKacc[dt][r] * idv * in;
            newV[rowoff + d] = om * vv + a * uVacc[dt][r] * idv;
        }
    }
    if (q == 0) {
        #pragma unroll
        for (int r = 0; r < 4; ++r) {
            int m = m0 + wv * 16 + 4 * g + r;
            float a = alr[r];
            float S = emS[pair * Mm + m];
            newS[pair * Mm + m] = fminf(fmaxf(S + a, 0.f), 3.0f);
            newAge[pair * Mm + m] = emAge[pair * Mm + m] * (1.f - a);
        }
    }
}

// =====================================================================
// ===================== FALLBACK KERNELS (verified) ===================
// =====================================================================
__global__ __launch_bounds__(256) void k1_fb(
    const float* __restrict__ seed, const float* __restrict__ emK, const float* __restrict__ emV,
    const float* __restrict__ emS, const float* __restrict__ w1, const float* __restrict__ w2,
    const float* __restrict__ gb, const float* __restrict__ rtau, float* __restrict__ y_em)
{
    const int bs = blockIdx.z, b = blockIdx.y, n0 = blockIdx.x * 64;
    const int tid = threadIdx.x;
    const int wv = tid >> 6, l = tid & 63, g = l >> 4, q = l & 15;

    __shared__ float yl[64][132];
    __shared__ ushort_t kl[64][136];
    __shared__ ushort_t vt[128][72];
    __shared__ float sw1[Dd], sw2[Dd], sgb[Dd];

    const float itau = 1.f / (softplusf(rtau[b]) + 0.1f);
    const size_t pair = (size_t)(bs * Bb + b);
    const float* Kb = emK + pair * (size_t)(Mm * Dd);
    const float* Vb = emV + pair * (size_t)(Mm * Dd);

    if (tid < Dd) {
        sw1[tid] = w1[b * Dd + tid];
        sw2[tid] = w2[b * Dd + tid];
        sgb[tid] = gb[b * Dd + tid];
    }
    unsigned long long mlo, mhi;
    build_mask(emS, pair, g, mlo, mhi);
    {
        const float4* s4 = (const float4*)(seed + ((size_t)bs * Nn + n0) * Dd);
        #pragma unroll
        for (int it = 0; it < 8; ++it) {
            int i = tid + it * 256;
            *(float4*)&yl[i >> 5][(i & 31) * 4] = s4[i];
        }
    }
    __syncthreads();

    const f32x4 Z4 = {0.f, 0.f, 0.f, 0.f};

    #pragma unroll 1
    for (int step = 0; step < 2; ++step) {
        short8v yf[4];
        #pragma unroll
        for (int ck = 0; ck < 4; ++ck) yf[ck] = build_yfrag(yl, wv * 16 + q, ck, g);

        float m_run = NEGV, l_run = 0.f;
        f32x4 dacc[8];
        #pragma unroll
        for (int dt = 0; dt < 8; ++dt) dacc[dt] = Z4;

        #pragma unroll 1
        for (int mc = 0; mc < 8; ++mc) {
            stage_K64(Kb + (size_t)mc * 64 * Dd, kl, tid);
            stage_VT(Vb + (size_t)mc * 64 * Dd, vt, tid);
            __syncthreads();

            f32x4 sc[4];
            #pragma unroll
            for (int mt = 0; mt < 4; ++mt) {
                f32x4 acc = Z4;
                #pragma unroll
                for (int ck = 0; ck < 4; ++ck)
                    acc = mfma16(read_kfrag(kl, mt, ck, g, q), yf[ck], acc);
                sc[mt] = acc;
            }
            unsigned au = (unsigned)(((mc < 4) ? mlo : mhi) >> ((mc & 3) * 16)) & 0xFFFFu;
            #pragma unroll
            for (int mt = 0; mt < 4; ++mt)
                #pragma unroll
                for (int r = 0; r < 4; ++r)
                    sc[mt][r] = ((au >> (mt * 4 + r)) & 1u) ? sc[mt][r] * itau : NEGV;
            float cm = NEGV;
            #pragma unroll
            for (int mt = 0; mt < 4; ++mt)
                #pragma unroll
                for (int r = 0; r < 4; ++r) cm = fmaxf(cm, sc[mt][r]);
            cm = fmaxf(cm, __shfl_xor(cm, 16));
            cm = fmaxf(cm, __shfl_xor(cm, 32));
            float mnew = fmaxf(m_run, cm);
            float corr = __expf(m_run - mnew);
            unsigned pw[8];
            float psum = 0.f;
            #pragma unroll
            for (int mt = 0; mt < 4; ++mt)
                #pragma unroll
                for (int r = 0; r < 4; r += 2) {
                    float e0 = __expf(sc[mt][r]     - mnew);
                    float e1 = __expf(sc[mt][r + 1] - mnew);
                    psum += e0 + e1;
                    pw[mt * 2 + (r >> 1)] = pack2bf(e0, e1);
                }
            psum += __shfl_xor(psum, 16);
            psum += __shfl_xor(psum, 32);
            l_run = l_run * corr + psum;
            m_run = mnew;
            float cr[4];
            #pragma unroll
            for (int r = 0; r < 4; ++r) cr[r] = __shfl(corr, 4 * g + r);
            #pragma unroll
            for (int dt = 0; dt < 8; ++dt)
                #pragma unroll
                for (int r = 0; r < 4; ++r) dacc[dt][r] *= cr[r];
            union { short8v s; uint4 u; } pa0, pa1;
            pa0.u = make_uint4(pw[0], pw[1], pw[2], pw[3]);
            pa1.u = make_uint4(pw[4], pw[5], pw[6], pw[7]);
            #pragma unroll
            for (int dt = 0; dt < 8; ++dt) {
                f32x4 acc = dacc[dt];
                acc = mfma16(pa0.s, read_vfrag(vt, 0, dt, g, q), acc);
                acc = mfma16(pa1.s, read_vfrag(vt, 1, dt, g, q), acc);
                dacc[dt] = acc;
            }
            __syncthreads();
        }
        float inv = (m_run != NEGV) ? 1.f / l_run : 0.f;
        float ivr[4];
        #pragma unroll
        for (int r = 0; r < 4; ++r) ivr[r] = __shfl(inv, 4 * g + r);
        #pragma unroll
        for (int r = 0; r < 4; ++r) {
            int row = wv * 16 + 4 * g + r;
            #pragma unroll
            for (int dt = 0; dt < 8; ++dt) {
                int d = dt * 16 + q;
                float del = dacc[dt][r] * ivr[r];
                float y0 = yl[row][d];
                float z = sw1[d] * y0 + sw2[d] * del + sgb[d];
                float gte = 1.f / (1.f + __expf(-z));
                yl[row][d] = y0 + gte * del;
            }
        }
        __syncthreads();
    }
    #pragma unroll
    for (int r16 = 0; r16 < 16; ++r16) {
        int n = n0 + wv * 16 + r16;
        float2 sv = *(const float2*)(seed + ((size_t)bs * Nn + n) * Dd + 2 * l);
        float2 ov;
        ov.x = yl[wv * 16 + r16][2 * l]     - sv.x;
        ov.y = yl[wv * 16 + r16][2 * l + 1] - sv.y;
        *(float2*)(y_em + (((size_t)bs * Nn + n) * Bb + b) * Dd + 2 * l) = ov;
    }
}

__global__ __launch_bounds__(256) void k2a_fb(
    const float* __restrict__ w_cand, const float* __restrict__ surprise,
    const float* __restrict__ emK, const float* __restrict__ emV, const float* __restrict__ emS,
    const float* __restrict__ rtau, const float* __restrict__ rtauw,
    float* __restrict__ delta_em, float* newV)
{
    const int bs = blockIdx.z, b = blockIdx.y, n0 = blockIdx.x * 64;
    const int tid = threadIdx.x;
    const int wv = tid >> 6, l = tid & 63, g = l >> 4, q = l & 15;

    __shared__ float yl[64][132];
    __shared__ ushort_t kl[64][136];
    __shared__ ushort_t vt[128][72];

    const float itau = 1.f / (softplusf(rtau[b]) + 0.1f);
    const float itw  = 1.f / (softplusf(rtauw[b]) + 0.1f);
    const size_t pair = (size_t)(bs * Bb + b);
    const float* Kb = emK + pair * (size_t)(Mm * Dd);
    const float* Vb = emV + pair * (size_t)(Mm * Dd);
    float* stats = newV + pair * (size_t)(Mm * Dd) + 448 * Dd;

    unsigned long long mlo, mhi;
    build_mask(emS, pair, g, mlo, mhi);
    {
        const float4* s4 = (const float4*)(w_cand + ((size_t)bs * Nn + n0) * Dd);
        #pragma unroll
        for (int it = 0; it < 8; ++it) {
            int i = tid + it * 256;
            *(float4*)&yl[i >> 5][(i & 31) * 4] = s4[i];
        }
    }
    __syncthreads();
    #pragma unroll
    for (int r = 0; r < 4; ++r) {
        int row = wv * 16 + 4 * g + r;
        float v8[8]; float p = 0.f;
        #pragma unroll
        for (int dt = 0; dt < 8; ++dt) { float v = yl[row][dt * 16 + q]; v8[dt] = v; p += v * v; }
        #pragma unroll
        for (int off = 1; off < 16; off <<= 1) p += __shfl_xor(p, off);
        float nrm = fmaxf(sqrtf(p), 1e-12f);
        float invn = 1.f / nrm;
        if (q == 0) stats[3072 + n0 + row] = nrm;
        #pragma unroll
        for (int dt = 0; dt < 8; ++dt) yl[row][dt * 16 + q] = v8[dt] * invn;
    }
    __syncthreads();

    const f32x4 Z4 = {0.f, 0.f, 0.f, 0.f};
    short8v yf[4];
    #pragma unroll
    for (int ck = 0; ck < 4; ++ck) yf[ck] = build_yfrag(yl, wv * 16 + q, ck, g);

    float m1 = NEGV, l1 = 0.f, m2 = NEGV, s2 = 0.f;
    f32x4 dacc[8];
    #pragma unroll
    for (int dt = 0; dt < 8; ++dt) dacc[dt] = Z4;

    #pragma unroll 1
    for (int mc = 0; mc < 8; ++mc) {
        stage_K64(Kb + (size_t)mc * 64 * Dd, kl, tid);
        stage_VT(Vb + (size_t)mc * 64 * Dd, vt, tid);
        __syncthreads();

        f32x4 sc[4];
        #pragma unroll
        for (int mt = 0; mt < 4; ++mt) {
            f32x4 acc = Z4;
            #pragma unroll
            for (int ck = 0; ck < 4; ++ck)
                acc = mfma16(read_kfrag(kl, mt, ck, g, q), yf[ck], acc);
            sc[mt] = acc;
        }
        unsigned au = (unsigned)(((mc < 4) ? mlo : mhi) >> ((mc & 3) * 16)) & 0xFFFFu;

        float cm2 = NEGV;
        #pragma unroll
        for (int mt = 0; mt < 4; ++mt)
            #pragma unroll
            for (int r = 0; r < 4; ++r) {
                float v = ((au >> (mt * 4 + r)) & 1u) ? sc[mt][r] * itw : NEGV;
                cm2 = fmaxf(cm2, v);
            }
        cm2 = fmaxf(cm2, __shfl_xor(cm2, 16));
        cm2 = fmaxf(cm2, __shfl_xor(cm2, 32));
        float mn2 = fmaxf(m2, cm2);
        float c2 = __expf(m2 - mn2);
        float ps2 = 0.f;
        #pragma unroll
        for (int mt = 0; mt < 4; ++mt)
            #pragma unroll
            for (int r = 0; r < 4; ++r) {
                float v = ((au >> (mt * 4 + r)) & 1u) ? sc[mt][r] * itw : NEGV;
                ps2 += __expf(v - mn2);
            }
        ps2 += __shfl_xor(ps2, 16);
        ps2 += __shfl_xor(ps2, 32);
        s2 = s2 * c2 + ps2;
        m2 = mn2;

        #pragma unroll
        for (int mt = 0; mt < 4; ++mt)
            #pragma unroll
            for (int r = 0; r < 4; ++r)
                sc[mt][r] = ((au >> (mt * 4 + r)) & 1u) ? sc[mt][r] * itau : NEGV;
        float cm = NEGV;
        #pragma unroll
        for (int mt = 0; mt < 4; ++mt)
            #pragma unroll
            for (int r = 0; r < 4; ++r) cm = fmaxf(cm, sc[mt][r]);
        cm = fmaxf(cm, __shfl_xor(cm, 16));
        cm = fmaxf(cm, __shfl_xor(cm, 32));
        float mnew = fmaxf(m1, cm);
        float corr = __expf(m1 - mnew);
        unsigned pw[8];
        float psum = 0.f;
        #pragma unroll
        for (int mt = 0; mt < 4; ++mt)
            #pragma unroll
            for (int r = 0; r < 4; r += 2) {
                float e0 = __expf(sc[mt][r]     - mnew);
                float e1 = __expf(sc[mt][r + 1] - mnew);
                psum += e0 + e1;
                pw[mt * 2 + (r >> 1)] = pack2bf(e0, e1);
            }
        psum += __shfl_xor(psum, 16);
        psum += __shfl_xor(psum, 32);
        l1 = l1 * corr + psum;
        m1 = mnew;
        float cr[4];
        #pragma unroll
        for (int r = 0; r < 4; ++r) cr[r] = __shfl(corr, 4 * g + r);
        #pragma unroll
        for (int dt = 0; dt < 8; ++dt)
            #pragma unroll
            for (int r = 0; r < 4; ++r) dacc[dt][r] *= cr[r];
        union { short8v s; uint4 u; } pa0, pa1;
        pa0.u = make_uint4(pw[0], pw[1], pw[2], pw[3]);
        pa1.u = make_uint4(pw[4], pw[5], pw[6], pw[7]);
        #pragma unroll
        for (int dt = 0; dt < 8; ++dt) {
            f32x4 acc = dacc[dt];
            acc = mfma16(pa0.s, read_vfrag(vt, 0, dt, g, q), acc);
            acc = mfma16(pa1.s, read_vfrag(vt, 1, dt, g, q), acc);
            dacc[dt] = acc;
        }
        __syncthreads();
    }
    if (g == 0) {
        int n = n0 + wv * 16 + q;
        stats[1024 + n] = m2;
        stats[2048 + n] = s2;
    }
    float inv1 = (m1 != NEGV) ? 1.f / l1 : 0.f;
    float ivr[4];
    #pragma unroll
    for (int r = 0; r < 4; ++r) ivr[r] = __shfl(inv1, 4 * g + r);
    #pragma unroll
    for (int r = 0; r < 4; ++r) {
        int n = n0 + wv * 16 + 4 * g + r;
        const float* wcr = w_cand + ((size_t)bs * Nn + n) * Dd;
        const float* spr = surprise + ((size_t)bs * Nn + n) * Dd;
        float pe = 0.f, ps = 0.f, wcv[8];
        #pragma unroll
        for (int dt = 0; dt < 8; ++dt) {
            float wc = wcr[dt * 16 + q];
            float rec = dacc[dt][r] * ivr[r];
            float df = wc - rec;
            pe += df * df;
            float sv = spr[dt * 16 + q];
            ps += sv * sv;
            wcv[dt] = wc;
        }
        #pragma unroll
        for (int off = 1; off < 16; off <<= 1) {
            pe += __shfl_xor(pe, off);
            ps += __shfl_xor(ps, off);
        }
        float novl = 0.5f * sqrtf(ps) + 0.5f * sqrtf(pe);
        if (q == 0) stats[n] = novl;
        float* der = delta_em + (((size_t)bs * Nn + n) * Bb + b) * Dd;
        #pragma unroll
        for (int dt = 0; dt < 8; ++dt) der[dt * 16 + q] = novl * wcv[dt];
    }
}

__global__ __launch_bounds__(256) void k2b_fb(
    const float* __restrict__ w_cand, const float* __restrict__ emK, const float* __restrict__ emV,
    const float* __restrict__ emS, const float* __restrict__ emAge,
    const float* __restrict__ g_em, const float* __restrict__ rtauw,
    float* __restrict__ newK, float* newV,
    float* __restrict__ newAge, float* __restrict__ newS, int mt_base)
{
    const int bs = blockIdx.z, b = blockIdx.y, mt = mt_base + blockIdx.x;
    const int m0 = mt * 64;
    const int tid = threadIdx.x;
    const int wv = tid >> 6, l = tid & 63, g = l >> 4, q = l & 15;

    __shared__ ushort_t klw[64][136];
    __shared__ ushort_t vtw[128][72];
    __shared__ float sh_rm[Nn], sh_f[Nn], sh_fn[Nn], sh_inv[Nn];

    const float itw = 1.f / (softplusf(rtauw[b]) + 0.1f);
    const float gv = g_em[bs * Bb + b];
    const size_t pair = (size_t)(bs * Bb + b);
    const float* stats = newV + pair * (size_t)(Mm * Dd) + 448 * Dd;

    for (int i = tid; i < Nn; i += 256) {
        float nv = stats[i];
        float rm = stats[1024 + i];
        float rs = stats[2048 + i];
        float nr = stats[3072 + i];
        sh_rm[i] = rm;
        float f = nv / rs;
        sh_f[i]  = f;
        sh_fn[i] = f * nr;
        sh_inv[i] = 1.f / nr;
    }

    const int myM = m0 + wv * 16 + q;
    const float* Krow = emK + (pair * Mm + myM) * (size_t)Dd;
    short8v kf[4];
    #pragma unroll
    for (int ck = 0; ck < 4; ++ck) {
        float4 a = *(const float4*)(Krow + ck * 32 + g * 8);
        float4 c = *(const float4*)(Krow + ck * 32 + g * 8 + 4);
        union { short8v s; uint4 u; } r;
        r.u.x = pack2bf(a.x, a.y);
        r.u.y = pack2bf(a.z, a.w);
        r.u.z = pack2bf(c.x, c.y);
        r.u.w = pack2bf(c.z, c.w);
        kf[ck] = r.s;
    }
    const bool act = (emS[pair * Mm + myM] > 0.f);

    const f32x4 Z4 = {0.f, 0.f, 0.f, 0.f};
    f32x4 uKacc[8], uVacc[8];
    #pragma unroll
    for (int dt = 0; dt < 8; ++dt) { uKacc[dt] = Z4; uVacc[dt] = Z4; }
    float den = 0.f;

    __syncthreads();

    #pragma unroll 1
    for (int nc = 0; nc < 16; ++nc) {
        const int nb = nc * 64;
        if (nc) __syncthreads();
        {
            const float4* s4 = (const float4*)(w_cand + ((size_t)bs * Nn + nb) * Dd);
            #pragma unroll
            for (int it = 0; it < 8; ++it) {
                int i = tid + it * 256;
                int m = i >> 5, c = i & 31;
                float4 v = s4[i];
                float inv = sh_inv[nb + m];
                uint2 w;
                w.x = pack2bf(v.x * inv, v.y * inv);
                w.y = pack2bf(v.z * inv, v.w * inv);
                *(uint2*)&klw[m][c * 4] = w;
            }
        }
        stage_WVT(w_cand + ((size_t)bs * Nn + nb) * Dd, sh_inv + nb, vtw, tid);
        __syncthreads();

        f32x4 sc[4];
        #pragma unroll
        for (int nt = 0; nt < 4; ++nt) {
            f32x4 acc = Z4;
            #pragma unroll
            for (int ck = 0; ck < 4; ++ck)
                acc = mfma16(read_kfrag(klw, nt, ck, g, q), kf[ck], acc);
            sc[nt] = acc;
        }
        unsigned pwK[8], pwV[8];
        #pragma unroll
        for (int nt = 0; nt < 4; ++nt) {
            float w0[4], w1[4];
            #pragma unroll
            for (int r = 0; r < 4; ++r) {
                int nl = nb + nt * 16 + 4 * g + r;
                float val = act ? sc[nt][r] * itw : NEGV;
                float E = __expf(val - sh_rm[nl]);
                float a = sh_f[nl] * E;
                w0[r] = a;
                w1[r] = sh_fn[nl] * E;
                den += a;
            }
            pwK[nt * 2 + 0] = pack2bf(w0[0], w0[1]);
            pwK[nt * 2 + 1] = pack2bf(w0[2], w0[3]);
            pwV[nt * 2 + 0] = pack2bf(w1[0], w1[1]);
            pwV[nt * 2 + 1] = pack2bf(w1[2], w1[3]);
        }
        union { short8v s; uint4 u; } paK0, paK1, paV0, paV1;
        paK0.u = make_uint4(pwK[0], pwK[1], pwK[2], pwK[3]);
        paK1.u = make_uint4(pwK[4], pwK[5], pwK[6], pwK[7]);
        paV0.u = make_uint4(pwV[0], pwV[1], pwV[2], pwV[3]);
        paV1.u = make_uint4(pwV[4], pwV[5], pwV[6], pwV[7]);
        #pragma unroll
        for (int dt = 0; dt < 8; ++dt) {
            short8v b0 = read_vfrag(vtw, 0, dt, g, q);
            short8v b1 = read_vfrag(vtw, 1, dt, g, q);
            uKacc[dt] = mfma16(paK0.s, b0, uKacc[dt]);
            uKacc[dt] = mfma16(paK1.s, b1, uKacc[dt]);
            uVacc[dt] = mfma16(paV0.s, b0, uVacc[dt]);
            uVacc[dt] = mfma16(paV1.s, b1, uVacc[dt]);
        }
    }

    den += __shfl_xor(den, 16);
    den += __shfl_xor(den, 32);
    float invd = 1.f / fmaxf(den, 1e-8f);
    float alpha = fminf(gv * den * (1.f / (float)Nn), 1.f);

    float pr[4] = {0.f, 0.f, 0.f, 0.f};
    #pragma unroll
    for (int dt = 0; dt < 8; ++dt)
        #pragma unroll
        for (int r = 0; r < 4; ++r) { float u = uKacc[dt][r]; pr[r] += u * u; }
    #pragma unroll
    for (int r = 0; r < 4; ++r) {
        #pragma unroll
        for (int off = 1; off < 16; off <<= 1) pr[r] += __shfl_xor(pr[r], off);
    }
    float alr[4], idr[4], inr[4];
    #pragma unroll
    for (int r = 0; r < 4; ++r) {
        alr[r] = __shfl(alpha, 4 * g + r);
        idr[r] = __shfl(invd,  4 * g + r);
        inr[r] = 1.f / fmaxf(sqrtf(pr[r]) * idr[r], 1e-12f);
    }
    #pragma unroll
    for (int r = 0; r < 4; ++r) {
        size_t rowoff = (pair * Mm + m0 + wv * 16 + 4 * g + r) * (size_t)Dd;
        float a = alr[r], om = 1.f - a, idv = idr[r], in = inr[r];
        #pragma unroll
        for (int dt = 0; dt < 8; ++dt) {
            int d = dt * 16 + q;
            float kv = emK[rowoff + d];
            float vv = emV[rowoff + d];
            newK[rowoff + d] = om * kv + a * uKacc[dt][r] * idv * in;
            newV[rowoff + d] = om * vv + a * uVacc[dt][r] * idv;
        }
    }
    if (q == 0) {
        #pragma unroll
        for (int r = 0; r < 4; ++r) {
            int m = m0 + wv * 16 + 4 * g + r;
            float a = alr[r];
            float S = emS[pair * Mm + m];
            newS[pair * Mm + m] = fminf(fmaxf(S + a, 0.f), 3.0f);
            newAge[pair * Mm + m] = emAge[pair * Mm + m] * (1.f - a);
        }
    }
}

// =====================================================================
// Kernel 2c: budget rescale of new_S in place (f32)
// =====================================================================
__global__ __launch_bounds__(256) void k2c_scale(float* newS)
{
    const int p = blockIdx.x, tid = threadIdx.x;
    __shared__ float red[256];
    float v0 = newS[(size_t)p * Mm + tid];
    float v1 = newS[(size_t)p * Mm + 256 + tid];
    red[tid] = v0 + v1;
    __syncthreads();
    for (int s = 128; s > 0; s >>= 1) {
        if (tid < s) red[tid] += red[tid + s];
        __syncthreads();
    }
    float tot = red[0];
    float sc = fminf(1.f, 32.0f / fmaxf(tot, 1e-8f));
    newS[(size_t)p * Mm + tid]       = v0 * sc;
    newS[(size_t)p * Mm + 256 + tid] = v1 * sc;
}

// =====================================================================
extern "C" void kernel_launch(void* const* d_in, const int* in_sizes, int n_in,
                              void* d_out, int out_size, void* d_ws, size_t ws_size,
                              hipStream_t stream)
{
    const float* seed     = (const float*)d_in[0];
    const float* w_cand   = (const float*)d_in[1];
    const float* surprise = (const float*)d_in[2];
    const float* g_em     = (const float*)d_in[3];
    const float* emK      = (const float*)d_in[4];
    const float* emV      = (const float*)d_in[5];
    const float* emS      = (const float*)d_in[6];
    const float* emAge    = (const float*)d_in[7];
    const float* w1       = (const float*)d_in[8];
    const float* w2       = (const float*)d_in[9];
    const float* gb       = (const float*)d_in[10];
    const float* rtau     = (const float*)d_in[11];
    const float* rtauw    = (const float*)d_in[12];

    float* out = (float*)d_out;
    float* y_em     = out;                            // (BS,N,B,D)  8388608
    float* delta_em = out + (size_t)8388608;          // (BS,N,B,D)  8388608
    float* newK     = out + (size_t)16777216;         // (BS,B,M,D)  4194304
    float* newV     = out + (size_t)20971520;         // (BS,B,M,D)  4194304
    float* newS     = out + (size_t)25165824;         // (BS,B,M)    32768
    float* newAge   = out + (size_t)25198592;         // (BS,B,M)    32768

    dim3 blk(256);

    // ws layout: Kbf 8.39MB | Vtb 8.39MB | wnr 2.10MB | wnT 2.10MB | nrm 32KB
    const size_t WS_NEED = 21004288;
    if (d_ws != nullptr && ws_size >= WS_NEED) {
        ushort_t* Kbf = (ushort_t*)d_ws;
        ushort_t* Vtb = Kbf + (size_t)64 * 65536;
        ushort_t* wnr = Vtb + (size_t)64 * 65536;
        ushort_t* wnT = wnr + (size_t)8 * 131072;
        float*    nrmb = (float*)(wnT + (size_t)8 * 131072);

        k0kv<<<dim3(512), blk, 0, stream>>>(emK, emV, Kbf, Vtb);
        k0w<<<dim3(128), blk, 0, stream>>>(w_cand, wnr, wnT, nrmb);
        k1_mono<<<dim3(1024), blk, 0, stream>>>(seed, Kbf, Vtb, emS, w1, w2, gb, rtau, y_em);
        k2a_pre<<<dim3(1024), blk, 0, stream>>>(w_cand, surprise, Kbf, Vtb, wnr, emS,
                                                rtau, rtauw, delta_em, newV);
        k2b_pre<<<dim3(448), blk, 0, stream>>>(wnr, wnT, Kbf, emK, emV, emS, emAge,
                                               g_em, rtauw, nrmb,
                                               newK, newV, newAge, newS, 0);
        k2b_pre<<<dim3(64), blk, 0, stream>>>(wnr, wnT, Kbf, emK, emV, emS, emAge,
                                              g_em, rtauw, nrmb,
                                              newK, newV, newAge, newS, 1);
    } else {
        dim3 g1(Nn / 64, Bb, BSz);
        k1_fb<<<g1, blk, 0, stream>>>(seed, emK, emV, emS, w1, w2, gb, rtau, y_em);
        k2a_fb<<<g1, blk, 0, stream>>>(w_cand, surprise, emK, emV, emS, rtau, rtauw,
                                       delta_em, newV);
        k2b_fb<<<dim3(7, Bb, BSz), blk, 0, stream>>>(w_cand, emK, emV, emS, emAge, g_em, rtauw,
                                                     newK, newV, newAge, newS, 0);
        k2b_fb<<<dim3(1, Bb, BSz), blk, 0, stream>>>(w_cand, emK, emV, emS, emAge, g_em, rtauw,
                                                     newK, newV, newAge, newS, 7);
    }
    k2c_scale<<<dim3(64), blk, 0, stream>>>(newS);
}